// Round 2
// baseline (2998.101 us; speedup 1.0000x reference)
//
#include <hip/hip_runtime.h>

// Problem constants (match reference)
#define NS   50000
#define ESS  800000
#define D    128

// ---------------------------------------------------------------------------
// Scatter-add aggregation: agg[dst] += x[src], cnt[dst] += 1 (layer 1 only).
// 32 threads per edge, each handling a float4 (16B) of the 512B feature row.
// ---------------------------------------------------------------------------
__global__ __launch_bounds__(256) void scatter_add_k(
    const float* __restrict__ x, const int* __restrict__ src,
    const int* __restrict__ dst, float* __restrict__ agg,
    float* __restrict__ cnt, int nedges, int do_cnt)
{
    int t = blockIdx.x * 256 + threadIdx.x;
    int e = t >> 5;
    if (e >= nedges) return;
    int c = (t & 31) << 2;          // float offset 0..124 step 4
    int s = src[e], d = dst[e];
    float4 v = *reinterpret_cast<const float4*>(x + (size_t)s * D + c);
    float* p = agg + (size_t)d * D + c;
    atomicAdd(p + 0, v.x);
    atomicAdd(p + 1, v.y);
    atomicAdd(p + 2, v.z);
    atomicAdd(p + 3, v.w);
    if (do_cnt && c == 0) atomicAdd(cnt + d, 1.0f);
}

// ---------------------------------------------------------------------------
// Fused SAGE linear: out = relu( (agg / max(cnt,1)) @ Wl + xin @ Wr + bias )
// Combined K=256 GEMM: k<128 -> agg/cnt with Wl, k>=128 -> xin with Wr.
// BM=32 rows/block, 256 threads, 4x4 register tile per thread, fp32.
// ---------------------------------------------------------------------------
__global__ __launch_bounds__(256) void fused_sage_linear(
    const float* __restrict__ agg, const float* __restrict__ cnt,
    const float* __restrict__ xin, const float* __restrict__ Wl,
    const float* __restrict__ Wr, const float* __restrict__ bias,
    float* __restrict__ out, int M)
{
    __shared__ float xt[32][64];     // 8 KB
    __shared__ float wt[64][128];    // 32 KB
    const int rb = blockIdx.x * 32;
    const int t  = threadIdx.x;
    const int tr = t >> 5;           // 0..7  -> rows tr*4 .. tr*4+3
    const int tc = t & 31;           // 0..31 -> cols tc*4 .. tc*4+3
    float acc[4][4] = {};

    for (int ks = 0; ks < 4; ++ks) {
        const int kbase = ks * 64;
        // ---- stage x tile (32 rows x 64 cols), 8 floats per thread ----
        {
            const int row  = t >> 3;          // 0..31
            const int col  = (t & 7) << 3;    // 0..56 step 8
            const int grow = rb + row;
            float4 v0 = make_float4(0.f, 0.f, 0.f, 0.f), v1 = v0;
            if (grow < M) {
                if (kbase < 128) {
                    const float* sp = agg + (size_t)grow * D + kbase + col;
                    float scale = 1.0f / fmaxf(cnt[grow], 1.0f);
                    v0 = *reinterpret_cast<const float4*>(sp);
                    v1 = *reinterpret_cast<const float4*>(sp + 4);
                    v0.x *= scale; v0.y *= scale; v0.z *= scale; v0.w *= scale;
                    v1.x *= scale; v1.y *= scale; v1.z *= scale; v1.w *= scale;
                } else {
                    const float* sp = xin + (size_t)grow * D + (kbase - 128) + col;
                    v0 = *reinterpret_cast<const float4*>(sp);
                    v1 = *reinterpret_cast<const float4*>(sp + 4);
                }
            }
            *reinterpret_cast<float4*>(&xt[row][col])     = v0;
            *reinterpret_cast<float4*>(&xt[row][col + 4]) = v1;
        }
        // ---- stage W tile (64 rows x 128 cols), 8 float4 per thread ----
        {
            const float* Wsrc = (kbase < 128) ? (Wl + (size_t)kbase * 128)
                                              : (Wr + (size_t)(kbase - 128) * 128);
            #pragma unroll
            for (int i = 0; i < 8; ++i) {
                int flat = i * 1024 + t * 4;
                int r = flat >> 7, cc = flat & 127;
                *reinterpret_cast<float4*>(&wt[r][cc]) =
                    *reinterpret_cast<const float4*>(Wsrc + flat);
            }
        }
        __syncthreads();
        // ---- compute ----
        #pragma unroll 8
        for (int k = 0; k < 64; ++k) {
            float4 wv = *reinterpret_cast<const float4*>(&wt[k][tc << 2]);
            #pragma unroll
            for (int j = 0; j < 4; ++j) {
                float xv = xt[(tr << 2) + j][k];
                acc[j][0] += xv * wv.x;
                acc[j][1] += xv * wv.y;
                acc[j][2] += xv * wv.z;
                acc[j][3] += xv * wv.w;
            }
        }
        __syncthreads();
    }
    // ---- epilogue: bias + relu + store ----
    #pragma unroll
    for (int j = 0; j < 4; ++j) {
        int grow = rb + (tr << 2) + j;
        if (grow >= M) continue;
        float4 o;
        int col = tc << 2;
        o.x = fmaxf(acc[j][0] + bias[col + 0], 0.f);
        o.y = fmaxf(acc[j][1] + bias[col + 1], 0.f);
        o.z = fmaxf(acc[j][2] + bias[col + 2], 0.f);
        o.w = fmaxf(acc[j][3] + bias[col + 3], 0.f);
        *reinterpret_cast<float4*>(out + (size_t)grow * D + col) = o;
    }
}

// ---------------------------------------------------------------------------
// Final projection: out[i][0:2] = s2[i] @ lin_w + lin_b. One wave per row.
// ---------------------------------------------------------------------------
__global__ __launch_bounds__(256) void final_linear_k(
    const float* __restrict__ s2, const float* __restrict__ lw,
    const float* __restrict__ lb, float* __restrict__ out, int M)
{
    int gid  = blockIdx.x * 256 + threadIdx.x;
    int row  = gid >> 6;
    int lane = threadIdx.x & 63;
    if (row >= M) return;
    float2 v = *reinterpret_cast<const float2*>(s2 + (size_t)row * D + (lane << 1));
    float4 w = *reinterpret_cast<const float4*>(lw + lane * 4);  // rows lane*2, lane*2+1 of [128][2]
    float a0 = v.x * w.x + v.y * w.z;
    float a1 = v.x * w.y + v.y * w.w;
    #pragma unroll
    for (int off = 32; off > 0; off >>= 1) {
        a0 += __shfl_xor(a0, off);
        a1 += __shfl_xor(a1, off);
    }
    if (lane == 0) {
        float2 o = make_float2(a0 + lb[0], a1 + lb[1]);
        *reinterpret_cast<float2*>(out + (size_t)row * 2) = o;
    }
}

// ---------------------------------------------------------------------------
extern "C" void kernel_launch(void* const* d_in, const int* in_sizes, int n_in,
                              void* d_out, int out_size, void* d_ws, size_t ws_size,
                              hipStream_t stream)
{
    // setup_inputs() dict order:
    // 0 x_subject, 1 x_roi,
    // 2..13: w1_sr_l, w1_sr_r, w1_rr_l, w1_rr_r, w1_ss_l, w1_ss_r,
    //        w2_sr_l, w2_sr_r, w2_rr_l, w2_rr_r, w2_ss_l, w2_ss_r
    // 14..19: b1_sr, b1_rr, b1_ss, b2_sr, b2_rr, b2_ss
    // 20 lin_w, 21 lin_b, 22..27: ei_sr_src, ei_sr_dst, ei_rr_src, ei_rr_dst,
    //                              ei_ss_src, ei_ss_dst
    const float* x_subject = (const float*)d_in[0];
    const float* w1l  = (const float*)d_in[6];
    const float* w1r  = (const float*)d_in[7];
    const float* w2l  = (const float*)d_in[12];
    const float* w2r  = (const float*)d_in[13];
    const float* b1   = (const float*)d_in[16];
    const float* b2   = (const float*)d_in[19];
    const float* linw = (const float*)d_in[20];
    const float* linb = (const float*)d_in[21];
    const int* ss_src = (const int*)d_in[26];
    const int* ss_dst = (const int*)d_in[27];

    // Workspace layout (ws poisoned 0xAA each call — zero what needs zeroing).
    // s2 aliases agg: in fused_sage_linear each block reads only its own 32
    // agg rows (ks=0,1) before writing the same rows in the epilogue.
    float* agg = (float*)d_ws;                    // NS*128 f32
    float* cnt = agg + (size_t)NS * D;            // NS f32
    float* s1  = cnt + NS;                        // NS*128 f32
    float* s2  = agg;                             // alias (safe, see above)

    hipMemsetAsync(agg, 0, ((size_t)NS * D + NS) * sizeof(float), stream);

    const int scatter_blocks = (ESS * 32) / 256;  // 100000
    const int lin_blocks     = (NS + 31) / 32;    // 1563

    // Layer 1 (subject->subject only; roi branch is dead code w.r.t. output)
    scatter_add_k<<<scatter_blocks, 256, 0, stream>>>(x_subject, ss_src, ss_dst,
                                                      agg, cnt, ESS, 1);
    fused_sage_linear<<<lin_blocks, 256, 0, stream>>>(agg, cnt, x_subject,
                                                      w1l, w1r, b1, s1, NS);
    // Layer 2 (same edge list -> same counts)
    hipMemsetAsync(agg, 0, (size_t)NS * D * sizeof(float), stream);
    scatter_add_k<<<scatter_blocks, 256, 0, stream>>>(s1, ss_src, ss_dst,
                                                      agg, cnt, ESS, 0);
    fused_sage_linear<<<lin_blocks, 256, 0, stream>>>(agg, cnt, s1,
                                                      w2l, w2r, b2, s2, NS);
    // Output projection
    final_linear_k<<<(NS * 64 + 255) / 256, 256, 0, stream>>>(s2, linw, linb,
                                                              (float*)d_out, NS);
}

// Round 3
// 622.919 us; speedup vs baseline: 4.8130x; 4.8130x over previous
//
#include <hip/hip_runtime.h>

// Problem constants (match reference)
#define NS   50000
#define ESS  800000
#define D    128

// ---------------------------------------------------------------------------
// CSR build step 1: deg[dst]++ per edge (int atomics, cheap).
// ---------------------------------------------------------------------------
__global__ __launch_bounds__(256) void count_deg_k(
    const int* __restrict__ dst, int* __restrict__ deg, int n)
{
    int e = blockIdx.x * 256 + threadIdx.x;
    if (e < n) atomicAdd(&deg[dst[e]], 1);
}

// ---------------------------------------------------------------------------
// CSR build step 2: single-block exclusive scan of deg -> row_start, pos.
// 1024 threads, each owns a contiguous chunk of ceil(n/1024) elements.
// ---------------------------------------------------------------------------
__global__ __launch_bounds__(1024) void scan_k(
    const int* __restrict__ deg, int* __restrict__ row_start,
    int* __restrict__ pos, int n)
{
    __shared__ int lds[1024];
    const int t = threadIdx.x;
    const int chunk = (n + 1023) / 1024;
    const int base = t * chunk;
    const int end  = min(base + chunk, n);
    int sum = 0;
    for (int i = base; i < end; ++i) sum += deg[i];
    lds[t] = sum;
    __syncthreads();
    // Hillis-Steele inclusive scan over 1024 partials
    for (int off = 1; off < 1024; off <<= 1) {
        int other = (t >= off) ? lds[t - off] : 0;
        __syncthreads();
        if (t >= off) lds[t] += other;
        __syncthreads();
    }
    int run = lds[t] - sum;  // exclusive prefix of this chunk
    for (int i = base; i < end; ++i) {
        row_start[i] = run;
        pos[i] = run;
        run += deg[i];
    }
}

// ---------------------------------------------------------------------------
// CSR build step 3: esrc[slot] = src[e], slot = pos[dst[e]]++.
// ---------------------------------------------------------------------------
__global__ __launch_bounds__(256) void fill_csr_k(
    const int* __restrict__ src, const int* __restrict__ dst,
    int* __restrict__ pos, int* __restrict__ esrc, int n)
{
    int e = blockIdx.x * 256 + threadIdx.x;
    if (e < n) {
        int slot = atomicAdd(&pos[dst[e]], 1);
        esrc[slot] = src[e];
    }
}

// ---------------------------------------------------------------------------
// Gather-mean: agg[d] = mean over in-edges of x[esrc[...]]. One wave per dst
// node, lane l owns float2 features [2l, 2l+1]; each edge read is a fully
// coalesced 512 B row (L2/LLC-resident). No feature atomics.
// ---------------------------------------------------------------------------
__global__ __launch_bounds__(256) void gather_mean_k(
    const float* __restrict__ x, const int* __restrict__ esrc,
    const int* __restrict__ row_start, const int* __restrict__ deg,
    float* __restrict__ agg, int M)
{
    int d = blockIdx.x * 4 + (threadIdx.x >> 6);
    if (d >= M) return;
    int lane = threadIdx.x & 63;
    int beg = row_start[d];
    int n   = deg[d];
    const float2* xp = reinterpret_cast<const float2*>(x);
    float ax = 0.f, ay = 0.f;
    for (int j = 0; j < n; ++j) {
        int s = esrc[beg + j];
        float2 v = xp[(size_t)s * 64 + lane];
        ax += v.x; ay += v.y;
    }
    float scale = 1.0f / fmaxf((float)n, 1.0f);
    reinterpret_cast<float2*>(agg)[(size_t)d * 64 + lane] =
        make_float2(ax * scale, ay * scale);
}

// ---------------------------------------------------------------------------
// Fused SAGE linear: out = relu( agg @ Wl + xin @ Wr + bias )   (agg = mean)
// Combined K=256 GEMM: k<128 -> agg with Wl, k>=128 -> xin with Wr.
// BM=32 rows/block, 256 threads, 4x4 register tile per thread, fp32.
// ---------------------------------------------------------------------------
__global__ __launch_bounds__(256) void fused_sage_linear(
    const float* __restrict__ agg, const float* __restrict__ xin,
    const float* __restrict__ Wl, const float* __restrict__ Wr,
    const float* __restrict__ bias, float* __restrict__ out, int M)
{
    __shared__ float xt[32][64];     // 8 KB
    __shared__ float wt[64][128];    // 32 KB
    const int rb = blockIdx.x * 32;
    const int t  = threadIdx.x;
    const int tr = t >> 5;           // 0..7  -> rows tr*4 .. tr*4+3
    const int tc = t & 31;           // 0..31 -> cols tc*4 .. tc*4+3
    float acc[4][4] = {};

    for (int ks = 0; ks < 4; ++ks) {
        const int kbase = ks * 64;
        // ---- stage x tile (32 rows x 64 cols), 8 floats per thread ----
        {
            const int row  = t >> 3;          // 0..31
            const int col  = (t & 7) << 3;    // 0..56 step 8
            const int grow = rb + row;
            float4 v0 = make_float4(0.f, 0.f, 0.f, 0.f), v1 = v0;
            if (grow < M) {
                const float* sp = (kbase < 128)
                    ? agg + (size_t)grow * D + kbase + col
                    : xin + (size_t)grow * D + (kbase - 128) + col;
                v0 = *reinterpret_cast<const float4*>(sp);
                v1 = *reinterpret_cast<const float4*>(sp + 4);
            }
            *reinterpret_cast<float4*>(&xt[row][col])     = v0;
            *reinterpret_cast<float4*>(&xt[row][col + 4]) = v1;
        }
        // ---- stage W tile (64 rows x 128 cols), 8 float4 per thread ----
        {
            const float* Wsrc = (kbase < 128) ? (Wl + (size_t)kbase * 128)
                                              : (Wr + (size_t)(kbase - 128) * 128);
            #pragma unroll
            for (int i = 0; i < 8; ++i) {
                int flat = i * 1024 + t * 4;
                int r = flat >> 7, cc = flat & 127;
                *reinterpret_cast<float4*>(&wt[r][cc]) =
                    *reinterpret_cast<const float4*>(Wsrc + flat);
            }
        }
        __syncthreads();
        // ---- compute ----
        #pragma unroll 8
        for (int k = 0; k < 64; ++k) {
            float4 wv = *reinterpret_cast<const float4*>(&wt[k][tc << 2]);
            #pragma unroll
            for (int j = 0; j < 4; ++j) {
                float xv = xt[(tr << 2) + j][k];
                acc[j][0] += xv * wv.x;
                acc[j][1] += xv * wv.y;
                acc[j][2] += xv * wv.z;
                acc[j][3] += xv * wv.w;
            }
        }
        __syncthreads();
    }
    // ---- epilogue: bias + relu + store ----
    #pragma unroll
    for (int j = 0; j < 4; ++j) {
        int grow = rb + (tr << 2) + j;
        if (grow >= M) continue;
        float4 o;
        int col = tc << 2;
        o.x = fmaxf(acc[j][0] + bias[col + 0], 0.f);
        o.y = fmaxf(acc[j][1] + bias[col + 1], 0.f);
        o.z = fmaxf(acc[j][2] + bias[col + 2], 0.f);
        o.w = fmaxf(acc[j][3] + bias[col + 3], 0.f);
        *reinterpret_cast<float4*>(out + (size_t)grow * D + col) = o;
    }
}

// ---------------------------------------------------------------------------
// Final projection: out[i][0:2] = s2[i] @ lin_w + lin_b. One wave per row.
// ---------------------------------------------------------------------------
__global__ __launch_bounds__(256) void final_linear_k(
    const float* __restrict__ s2, const float* __restrict__ lw,
    const float* __restrict__ lb, float* __restrict__ out, int M)
{
    int gid  = blockIdx.x * 256 + threadIdx.x;
    int row  = gid >> 6;
    int lane = threadIdx.x & 63;
    if (row >= M) return;
    float2 v = *reinterpret_cast<const float2*>(s2 + (size_t)row * D + (lane << 1));
    float4 w = *reinterpret_cast<const float4*>(lw + lane * 4);  // rows lane*2, lane*2+1 of [128][2]
    float a0 = v.x * w.x + v.y * w.z;
    float a1 = v.x * w.y + v.y * w.w;
    #pragma unroll
    for (int off = 32; off > 0; off >>= 1) {
        a0 += __shfl_xor(a0, off);
        a1 += __shfl_xor(a1, off);
    }
    if (lane == 0) {
        float2 o = make_float2(a0 + lb[0], a1 + lb[1]);
        *reinterpret_cast<float2*>(out + (size_t)row * 2) = o;
    }
}

// ---------------------------------------------------------------------------
extern "C" void kernel_launch(void* const* d_in, const int* in_sizes, int n_in,
                              void* d_out, int out_size, void* d_ws, size_t ws_size,
                              hipStream_t stream)
{
    // setup_inputs() dict order: 0 x_subject, 1 x_roi, 2..13 weights,
    // 14..19 biases, 20 lin_w, 21 lin_b, 22..27 edge indices.
    const float* x_subject = (const float*)d_in[0];
    const float* w1l  = (const float*)d_in[6];
    const float* w1r  = (const float*)d_in[7];
    const float* w2l  = (const float*)d_in[12];
    const float* w2r  = (const float*)d_in[13];
    const float* b1   = (const float*)d_in[16];
    const float* b2   = (const float*)d_in[19];
    const float* linw = (const float*)d_in[20];
    const float* linb = (const float*)d_in[21];
    const int* ss_src = (const int*)d_in[26];
    const int* ss_dst = (const int*)d_in[27];

    // Workspace layout (re-poisoned 0xAA each call; zero what needs zeroing):
    //  agg:       NS*128 f32 (25.6 MB) — mean-aggregated features
    //  s1:        NS*128 f32 (25.6 MB)
    //  deg/row_start/pos: NS int each
    //  esrc:      ESS int (3.2 MB) — CSR-sorted source indices
    // s2 aliases agg (each GEMM block reads only its own agg rows before
    // writing the same rows in the epilogue).
    float* agg       = (float*)d_ws;
    float* s1        = agg + (size_t)NS * D;
    int*   deg       = (int*)(s1 + (size_t)NS * D);
    int*   row_start = deg + NS;
    int*   pos       = row_start + NS;
    int*   esrc      = pos + NS;
    float* s2        = agg;  // alias (safe, see above)

    const int edge_blocks = (ESS + 255) / 256;   // 3125
    const int lin_blocks  = (NS + 31) / 32;      // 1563
    const int gath_blocks = (NS + 3) / 4;        // 12500

    // ---- CSR build (edge list shared by both layers; rebuilt every call) ----
    hipMemsetAsync(deg, 0, NS * sizeof(int), stream);
    count_deg_k<<<edge_blocks, 256, 0, stream>>>(ss_dst, deg, ESS);
    scan_k<<<1, 1024, 0, stream>>>(deg, row_start, pos, NS);
    fill_csr_k<<<edge_blocks, 256, 0, stream>>>(ss_src, ss_dst, pos, esrc, ESS);

    // ---- Layer 1 (roi branch is dead code w.r.t. the output) ----
    gather_mean_k<<<gath_blocks, 256, 0, stream>>>(x_subject, esrc, row_start,
                                                   deg, agg, NS);
    fused_sage_linear<<<lin_blocks, 256, 0, stream>>>(agg, x_subject,
                                                      w1l, w1r, b1, s1, NS);
    // ---- Layer 2 (same edge list -> same CSR) ----
    gather_mean_k<<<gath_blocks, 256, 0, stream>>>(s1, esrc, row_start,
                                                   deg, agg, NS);
    fused_sage_linear<<<lin_blocks, 256, 0, stream>>>(agg, s1,
                                                      w2l, w2r, b2, s2, NS);
    // ---- Output projection ----
    final_linear_k<<<(NS * 64 + 255) / 256, 256, 0, stream>>>(s2, linw, linb,
                                                              (float*)d_out, NS);
}

// Round 4
// 474.815 us; speedup vs baseline: 6.3143x; 1.3119x over previous
//
#include <hip/hip_runtime.h>

// Problem constants (match reference)
#define NS   50000
#define ESS  800000
#define D    128
#define SCAN_BLOCKS ((NS + 255) / 256)   // 196

// ---------------------------------------------------------------------------
// CSR build step 1: deg[dst]++ per edge (int atomics, cheap).
// ---------------------------------------------------------------------------
__global__ __launch_bounds__(256) void count_deg_k(
    const int* __restrict__ dst, int* __restrict__ deg, int n)
{
    int e = blockIdx.x * 256 + threadIdx.x;
    if (e < n) atomicAdd(&deg[dst[e]], 1);
}

// ---------------------------------------------------------------------------
// Hierarchical scan, stage A: per-block (256 elems) sum of deg -> bsum.
// ---------------------------------------------------------------------------
__global__ __launch_bounds__(256) void block_sum_k(
    const int* __restrict__ deg, int* __restrict__ bsum, int n)
{
    __shared__ int lds[256];
    int i = blockIdx.x * 256 + threadIdx.x;
    int v = (i < n) ? deg[i] : 0;
    lds[threadIdx.x] = v;
    __syncthreads();
    for (int off = 128; off > 0; off >>= 1) {
        if (threadIdx.x < off) lds[threadIdx.x] += lds[threadIdx.x + off];
        __syncthreads();
    }
    if (threadIdx.x == 0) bsum[blockIdx.x] = lds[0];
}

// ---------------------------------------------------------------------------
// Stage B: single small block scans the 196 partials -> exclusive boff.
// ---------------------------------------------------------------------------
__global__ __launch_bounds__(256) void scan_partials_k(
    const int* __restrict__ bsum, int* __restrict__ boff, int nb)
{
    __shared__ int lds[256];
    int t = threadIdx.x;
    int v = (t < nb) ? bsum[t] : 0;
    lds[t] = v;
    __syncthreads();
    for (int off = 1; off < 256; off <<= 1) {
        int other = (t >= off) ? lds[t - off] : 0;
        __syncthreads();
        lds[t] += other;
        __syncthreads();
    }
    if (t < nb) boff[t] = lds[t] - v;   // exclusive
}

// ---------------------------------------------------------------------------
// Stage C: intra-block exclusive scan + block offset -> row_start, pos.
// ---------------------------------------------------------------------------
__global__ __launch_bounds__(256) void scan_final_k(
    const int* __restrict__ deg, const int* __restrict__ boff,
    int* __restrict__ row_start, int* __restrict__ pos, int n)
{
    __shared__ int lds[256];
    int t = threadIdx.x;
    int i = blockIdx.x * 256 + t;
    int v = (i < n) ? deg[i] : 0;
    lds[t] = v;
    __syncthreads();
    for (int off = 1; off < 256; off <<= 1) {
        int other = (t >= off) ? lds[t - off] : 0;
        __syncthreads();
        lds[t] += other;
        __syncthreads();
    }
    if (i < n) {
        int rs = boff[blockIdx.x] + lds[t] - v;   // exclusive prefix
        row_start[i] = rs;
        pos[i] = rs;
    }
}

// ---------------------------------------------------------------------------
// CSR build step 3: esrc[slot] = src[e], slot = pos[dst[e]]++.
// ---------------------------------------------------------------------------
__global__ __launch_bounds__(256) void fill_csr_k(
    const int* __restrict__ src, const int* __restrict__ dst,
    int* __restrict__ pos, int* __restrict__ esrc, int n)
{
    int e = blockIdx.x * 256 + threadIdx.x;
    if (e < n) {
        int slot = atomicAdd(&pos[dst[e]], 1);
        esrc[slot] = src[e];
    }
}

// ---------------------------------------------------------------------------
// Gather-mean: agg[d] = mean over in-edges of x[esrc[...]]. One wave per dst
// node, lane l owns float2 features [2l, 2l+1]. Edge loop unrolled x4 with
// independent accumulators for memory-level parallelism (index load ->
// dependent row load chain otherwise limits to 1 outstanding row/wave).
// ---------------------------------------------------------------------------
__global__ __launch_bounds__(256) void gather_mean_k(
    const float* __restrict__ x, const int* __restrict__ esrc,
    const int* __restrict__ row_start, const int* __restrict__ deg,
    float* __restrict__ agg, int M)
{
    int d = blockIdx.x * 4 + (threadIdx.x >> 6);
    if (d >= M) return;
    int lane = threadIdx.x & 63;
    int beg = row_start[d];
    int n   = deg[d];
    const float2* xp = reinterpret_cast<const float2*>(x);
    float a0x = 0.f, a0y = 0.f, a1x = 0.f, a1y = 0.f;
    float a2x = 0.f, a2y = 0.f, a3x = 0.f, a3y = 0.f;
    int j = 0;
    for (; j + 3 < n; j += 4) {
        int s0 = esrc[beg + j + 0];
        int s1 = esrc[beg + j + 1];
        int s2 = esrc[beg + j + 2];
        int s3 = esrc[beg + j + 3];
        float2 v0 = xp[(size_t)s0 * 64 + lane];
        float2 v1 = xp[(size_t)s1 * 64 + lane];
        float2 v2 = xp[(size_t)s2 * 64 + lane];
        float2 v3 = xp[(size_t)s3 * 64 + lane];
        a0x += v0.x; a0y += v0.y;
        a1x += v1.x; a1y += v1.y;
        a2x += v2.x; a2y += v2.y;
        a3x += v3.x; a3y += v3.y;
    }
    for (; j < n; ++j) {
        int s = esrc[beg + j];
        float2 v = xp[(size_t)s * 64 + lane];
        a0x += v.x; a0y += v.y;
    }
    float ax = (a0x + a1x) + (a2x + a3x);
    float ay = (a0y + a1y) + (a2y + a3y);
    float scale = 1.0f / fmaxf((float)n, 1.0f);
    reinterpret_cast<float2*>(agg)[(size_t)d * 64 + lane] =
        make_float2(ax * scale, ay * scale);
}

// ---------------------------------------------------------------------------
// Fused SAGE linear: out = relu( agg @ Wl + xin @ Wr + bias )   (agg = mean)
// Combined K=256 GEMM: k<128 -> agg with Wl, k>=128 -> xin with Wr.
// BM=32 rows/block, 256 threads, 4x4 register tile per thread, fp32.
// ---------------------------------------------------------------------------
__global__ __launch_bounds__(256) void fused_sage_linear(
    const float* __restrict__ agg, const float* __restrict__ xin,
    const float* __restrict__ Wl, const float* __restrict__ Wr,
    const float* __restrict__ bias, float* __restrict__ out, int M)
{
    __shared__ float xt[32][64];     // 8 KB
    __shared__ float wt[64][128];    // 32 KB
    const int rb = blockIdx.x * 32;
    const int t  = threadIdx.x;
    const int tr = t >> 5;           // 0..7  -> rows tr*4 .. tr*4+3
    const int tc = t & 31;           // 0..31 -> cols tc*4 .. tc*4+3
    float acc[4][4] = {};

    for (int ks = 0; ks < 4; ++ks) {
        const int kbase = ks * 64;
        // ---- stage x tile (32 rows x 64 cols), 8 floats per thread ----
        {
            const int row  = t >> 3;          // 0..31
            const int col  = (t & 7) << 3;    // 0..56 step 8
            const int grow = rb + row;
            float4 v0 = make_float4(0.f, 0.f, 0.f, 0.f), v1 = v0;
            if (grow < M) {
                const float* sp = (kbase < 128)
                    ? agg + (size_t)grow * D + kbase + col
                    : xin + (size_t)grow * D + (kbase - 128) + col;
                v0 = *reinterpret_cast<const float4*>(sp);
                v1 = *reinterpret_cast<const float4*>(sp + 4);
            }
            *reinterpret_cast<float4*>(&xt[row][col])     = v0;
            *reinterpret_cast<float4*>(&xt[row][col + 4]) = v1;
        }
        // ---- stage W tile (64 rows x 128 cols), 8 float4 per thread ----
        {
            const float* Wsrc = (kbase < 128) ? (Wl + (size_t)kbase * 128)
                                              : (Wr + (size_t)(kbase - 128) * 128);
            #pragma unroll
            for (int i = 0; i < 8; ++i) {
                int flat = i * 1024 + t * 4;
                int r = flat >> 7, cc = flat & 127;
                *reinterpret_cast<float4*>(&wt[r][cc]) =
                    *reinterpret_cast<const float4*>(Wsrc + flat);
            }
        }
        __syncthreads();
        // ---- compute ----
        #pragma unroll 8
        for (int k = 0; k < 64; ++k) {
            float4 wv = *reinterpret_cast<const float4*>(&wt[k][tc << 2]);
            #pragma unroll
            for (int j = 0; j < 4; ++j) {
                float xv = xt[(tr << 2) + j][k];
                acc[j][0] += xv * wv.x;
                acc[j][1] += xv * wv.y;
                acc[j][2] += xv * wv.z;
                acc[j][3] += xv * wv.w;
            }
        }
        __syncthreads();
    }
    // ---- epilogue: bias + relu + store ----
    #pragma unroll
    for (int j = 0; j < 4; ++j) {
        int grow = rb + (tr << 2) + j;
        if (grow >= M) continue;
        float4 o;
        int col = tc << 2;
        o.x = fmaxf(acc[j][0] + bias[col + 0], 0.f);
        o.y = fmaxf(acc[j][1] + bias[col + 1], 0.f);
        o.z = fmaxf(acc[j][2] + bias[col + 2], 0.f);
        o.w = fmaxf(acc[j][3] + bias[col + 3], 0.f);
        *reinterpret_cast<float4*>(out + (size_t)grow * D + col) = o;
    }
}

// ---------------------------------------------------------------------------
// Final projection: out[i][0:2] = s2[i] @ lin_w + lin_b. One wave per row.
// ---------------------------------------------------------------------------
__global__ __launch_bounds__(256) void final_linear_k(
    const float* __restrict__ s2, const float* __restrict__ lw,
    const float* __restrict__ lb, float* __restrict__ out, int M)
{
    int gid  = blockIdx.x * 256 + threadIdx.x;
    int row  = gid >> 6;
    int lane = threadIdx.x & 63;
    if (row >= M) return;
    float2 v = *reinterpret_cast<const float2*>(s2 + (size_t)row * D + (lane << 1));
    float4 w = *reinterpret_cast<const float4*>(lw + lane * 4);
    float a0 = v.x * w.x + v.y * w.z;
    float a1 = v.x * w.y + v.y * w.w;
    #pragma unroll
    for (int off = 32; off > 0; off >>= 1) {
        a0 += __shfl_xor(a0, off);
        a1 += __shfl_xor(a1, off);
    }
    if (lane == 0) {
        float2 o = make_float2(a0 + lb[0], a1 + lb[1]);
        *reinterpret_cast<float2*>(out + (size_t)row * 2) = o;
    }
}

// ---------------------------------------------------------------------------
extern "C" void kernel_launch(void* const* d_in, const int* in_sizes, int n_in,
                              void* d_out, int out_size, void* d_ws, size_t ws_size,
                              hipStream_t stream)
{
    const float* x_subject = (const float*)d_in[0];
    const float* w1l  = (const float*)d_in[6];
    const float* w1r  = (const float*)d_in[7];
    const float* w2l  = (const float*)d_in[12];
    const float* w2r  = (const float*)d_in[13];
    const float* b1   = (const float*)d_in[16];
    const float* b2   = (const float*)d_in[19];
    const float* linw = (const float*)d_in[20];
    const float* linb = (const float*)d_in[21];
    const int* ss_src = (const int*)d_in[26];
    const int* ss_dst = (const int*)d_in[27];

    // Workspace layout (re-poisoned 0xAA each call):
    float* agg       = (float*)d_ws;                 // NS*128 f32
    float* s1        = agg + (size_t)NS * D;         // NS*128 f32
    int*   deg       = (int*)(s1 + (size_t)NS * D);  // NS int
    int*   row_start = deg + NS;                     // NS int
    int*   pos       = row_start + NS;               // NS int
    int*   esrc      = pos + NS;                     // ESS int
    int*   bsum      = esrc + ESS;                   // SCAN_BLOCKS int
    int*   boff      = bsum + SCAN_BLOCKS;           // SCAN_BLOCKS int
    float* s2        = agg;  // alias (safe: each GEMM block reads only its
                             // own agg rows before writing them)

    const int edge_blocks = (ESS + 255) / 256;   // 3125
    const int lin_blocks  = (NS + 31) / 32;      // 1563
    const int gath_blocks = (NS + 3) / 4;        // 12500

    // ---- CSR build (edge list shared by both layers) ----
    hipMemsetAsync(deg, 0, NS * sizeof(int), stream);
    count_deg_k<<<edge_blocks, 256, 0, stream>>>(ss_dst, deg, ESS);
    block_sum_k<<<SCAN_BLOCKS, 256, 0, stream>>>(deg, bsum, NS);
    scan_partials_k<<<1, 256, 0, stream>>>(bsum, boff, SCAN_BLOCKS);
    scan_final_k<<<SCAN_BLOCKS, 256, 0, stream>>>(deg, boff, row_start, pos, NS);
    fill_csr_k<<<edge_blocks, 256, 0, stream>>>(ss_src, ss_dst, pos, esrc, ESS);

    // ---- Layer 1 (roi branch is dead code w.r.t. the output) ----
    gather_mean_k<<<gath_blocks, 256, 0, stream>>>(x_subject, esrc, row_start,
                                                   deg, agg, NS);
    fused_sage_linear<<<lin_blocks, 256, 0, stream>>>(agg, x_subject,
                                                      w1l, w1r, b1, s1, NS);
    // ---- Layer 2 (same edge list -> same CSR) ----
    gather_mean_k<<<gath_blocks, 256, 0, stream>>>(s1, esrc, row_start,
                                                   deg, agg, NS);
    fused_sage_linear<<<lin_blocks, 256, 0, stream>>>(agg, s1,
                                                      w2l, w2r, b2, s2, NS);
    // ---- Output projection ----
    final_linear_k<<<(NS * 64 + 255) / 256, 256, 0, stream>>>(s2, linw, linb,
                                                              (float*)d_out, NS);
}

// Round 5
// 358.671 us; speedup vs baseline: 8.3589x; 1.3238x over previous
//
#include <hip/hip_runtime.h>

// Problem constants (match reference)
#define NS   50000
#define ESS  800000
#define D    128
#define SCAN_BLOCKS ((NS + 255) / 256)   // 196

typedef __attribute__((ext_vector_type(8))) short bf16x8;
typedef __attribute__((ext_vector_type(4))) float f32x4;

// f32 -> bf16 round-to-nearest-even (bits)
static __device__ __forceinline__ ushort f2bf(float f) {
    uint u = __float_as_uint(f);
    u += 0x7fffu + ((u >> 16) & 1u);
    return (ushort)(u >> 16);
}
static __device__ __forceinline__ float bf2f(ushort h) {
    return __uint_as_float((uint)h << 16);
}

// ---------------------------------------------------------------------------
// Split x_subject (f32) -> bf16 hi plane. 8 elems/thread.
// ---------------------------------------------------------------------------
__global__ __launch_bounds__(256) void split_x_k(
    const float* __restrict__ x, ushort* __restrict__ xh, int n8)
{
    int i = blockIdx.x * 256 + threadIdx.x;
    if (i >= n8) return;
    const float4* src = (const float4*)(x + (size_t)i * 8);
    float4 a = src[0], b = src[1];
    uint4 o;
    o.x = (uint)f2bf(a.x) | ((uint)f2bf(a.y) << 16);
    o.y = (uint)f2bf(a.z) | ((uint)f2bf(a.w) << 16);
    o.z = (uint)f2bf(b.x) | ((uint)f2bf(b.y) << 16);
    o.w = (uint)f2bf(b.z) | ((uint)f2bf(b.w) << 16);
    *(uint4*)(xh + (size_t)i * 8) = o;
}

// ---------------------------------------------------------------------------
// Prep W: combined [Wl;Wr] (256x128 f32) -> hi/lo bf16 planes in the MFMA
// staging layout: elem index = (((k>>5)*4 + ((k>>3)&3))*128 + col)*8 + (k&7).
// Covers both layers (layer = tid >> 15).
// ---------------------------------------------------------------------------
__global__ __launch_bounds__(256) void prep_w_k(
    const float* __restrict__ w1l, const float* __restrict__ w1r,
    const float* __restrict__ w2l, const float* __restrict__ w2r,
    ushort* __restrict__ wt1h, ushort* __restrict__ wt1l,
    ushort* __restrict__ wt2h, ushort* __restrict__ wt2l)
{
    int t = blockIdx.x * 256 + threadIdx.x;   // 0 .. 65535
    int layer = t >> 15;
    int rem   = t & 32767;
    int k     = rem >> 7;
    int col   = rem & 127;
    const float* wl = layer ? w2l : w1l;
    const float* wr = layer ? w2r : w1r;
    float v = (k < 128) ? wl[k * 128 + col] : wr[(k - 128) * 128 + col];
    ushort h = f2bf(v);
    ushort l = f2bf(v - bf2f(h));
    size_t idx = ((size_t)((k >> 5) * 4 + ((k >> 3) & 3)) * 128 + col) * 8 + (k & 7);
    ushort* dh = layer ? wt2h : wt1h;
    ushort* dl = layer ? wt2l : wt1l;
    dh[idx] = h;
    dl[idx] = l;
}

// ---------------------------------------------------------------------------
// CSR build (unchanged from R4)
// ---------------------------------------------------------------------------
__global__ __launch_bounds__(256) void count_deg_k(
    const int* __restrict__ dst, int* __restrict__ deg, int n)
{
    int e = blockIdx.x * 256 + threadIdx.x;
    if (e < n) atomicAdd(&deg[dst[e]], 1);
}

__global__ __launch_bounds__(256) void block_sum_k(
    const int* __restrict__ deg, int* __restrict__ bsum, int n)
{
    __shared__ int lds[256];
    int i = blockIdx.x * 256 + threadIdx.x;
    int v = (i < n) ? deg[i] : 0;
    lds[threadIdx.x] = v;
    __syncthreads();
    for (int off = 128; off > 0; off >>= 1) {
        if (threadIdx.x < off) lds[threadIdx.x] += lds[threadIdx.x + off];
        __syncthreads();
    }
    if (threadIdx.x == 0) bsum[blockIdx.x] = lds[0];
}

__global__ __launch_bounds__(256) void scan_partials_k(
    const int* __restrict__ bsum, int* __restrict__ boff, int nb)
{
    __shared__ int lds[256];
    int t = threadIdx.x;
    int v = (t < nb) ? bsum[t] : 0;
    lds[t] = v;
    __syncthreads();
    for (int off = 1; off < 256; off <<= 1) {
        int other = (t >= off) ? lds[t - off] : 0;
        __syncthreads();
        lds[t] += other;
        __syncthreads();
    }
    if (t < nb) boff[t] = lds[t] - v;
}

__global__ __launch_bounds__(256) void scan_final_k(
    const int* __restrict__ deg, const int* __restrict__ boff,
    int* __restrict__ row_start, int* __restrict__ pos, int n)
{
    __shared__ int lds[256];
    int t = threadIdx.x;
    int i = blockIdx.x * 256 + t;
    int v = (i < n) ? deg[i] : 0;
    lds[t] = v;
    __syncthreads();
    for (int off = 1; off < 256; off <<= 1) {
        int other = (t >= off) ? lds[t - off] : 0;
        __syncthreads();
        lds[t] += other;
        __syncthreads();
    }
    if (i < n) {
        int rs = boff[blockIdx.x] + lds[t] - v;
        row_start[i] = rs;
        pos[i] = rs;
    }
}

__global__ __launch_bounds__(256) void fill_csr_k(
    const int* __restrict__ src, const int* __restrict__ dst,
    int* __restrict__ pos, int* __restrict__ esrc, int n)
{
    int e = blockIdx.x * 256 + threadIdx.x;
    if (e < n) {
        int slot = atomicAdd(&pos[dst[e]], 1);
        esrc[slot] = src[e];
    }
}

// ---------------------------------------------------------------------------
// Gather-mean over bf16 rows: one wave per dst node, lane owns 2 bf16 (1 u32).
// Accumulate f32, write agg as hi/lo bf16 planes (split in epilogue).
// ---------------------------------------------------------------------------
__global__ __launch_bounds__(256) void gather_mean_bf16_k(
    const ushort* __restrict__ xh, const int* __restrict__ esrc,
    const int* __restrict__ row_start, const int* __restrict__ deg,
    ushort* __restrict__ aggh, ushort* __restrict__ aggl, int M)
{
    int d = blockIdx.x * 4 + (threadIdx.x >> 6);
    if (d >= M) return;
    int lane = threadIdx.x & 63;
    int beg = row_start[d];
    int n   = deg[d];
    const uint* xp = reinterpret_cast<const uint*>(xh);
    float a0x = 0.f, a0y = 0.f, a1x = 0.f, a1y = 0.f;
    float a2x = 0.f, a2y = 0.f, a3x = 0.f, a3y = 0.f;
    int j = 0;
    for (; j + 3 < n; j += 4) {
        int s0 = esrc[beg + j + 0];
        int s1 = esrc[beg + j + 1];
        int s2 = esrc[beg + j + 2];
        int s3 = esrc[beg + j + 3];
        uint u0 = xp[(size_t)s0 * 64 + lane];
        uint u1 = xp[(size_t)s1 * 64 + lane];
        uint u2 = xp[(size_t)s2 * 64 + lane];
        uint u3 = xp[(size_t)s3 * 64 + lane];
        a0x += __uint_as_float(u0 << 16); a0y += __uint_as_float(u0 & 0xffff0000u);
        a1x += __uint_as_float(u1 << 16); a1y += __uint_as_float(u1 & 0xffff0000u);
        a2x += __uint_as_float(u2 << 16); a2y += __uint_as_float(u2 & 0xffff0000u);
        a3x += __uint_as_float(u3 << 16); a3y += __uint_as_float(u3 & 0xffff0000u);
    }
    for (; j < n; ++j) {
        int s = esrc[beg + j];
        uint u = xp[(size_t)s * 64 + lane];
        a0x += __uint_as_float(u << 16); a0y += __uint_as_float(u & 0xffff0000u);
    }
    float ax = ((a0x + a1x) + (a2x + a3x));
    float ay = ((a0y + a1y) + (a2y + a3y));
    float scale = 1.0f / fmaxf((float)n, 1.0f);
    ax *= scale; ay *= scale;
    ushort hx = f2bf(ax), hy = f2bf(ay);
    ushort lx = f2bf(ax - bf2f(hx)), ly = f2bf(ay - bf2f(hy));
    reinterpret_cast<uint*>(aggh)[(size_t)d * 64 + lane] = (uint)hx | ((uint)hy << 16);
    reinterpret_cast<uint*>(aggl)[(size_t)d * 64 + lane] = (uint)lx | ((uint)ly << 16);
}

// ---------------------------------------------------------------------------
// MFMA SAGE linear. out_row = relu([agg | x] @ [Wl;Wr] + bias), where the agg
// half uses split-bf16 compensation (Ah*Bh + Ah*Bl + Al*Bh) and the x half
// uses hi-only A (Ah*Bh + Ah*Bl). f32 accumulation throughout.
// Block: 256 thr = 4 waves (2x2), tile 64 rows x 128 cols, K=256 in 8 steps.
// FINAL=false: write s1 bf16-hi. FINAL=true: fuse 128->2 projection,
// atomicAdd into zeroed d_out (2 waves contribute per row).
// mfma_f32_16x16x32_bf16 layouts: A row=lane&15, k=(lane>>4)*8+e;
// B col=lane&15, k=(lane>>4)*8+e; D col=lane&15, row=(lane>>4)*4+reg (m89).
// ---------------------------------------------------------------------------
template<bool FINAL>
__global__ __launch_bounds__(256) void sage_mfma_k(
    const ushort* __restrict__ aggh, const ushort* __restrict__ aggl,
    const ushort* __restrict__ xh,
    const ushort* __restrict__ wth, const ushort* __restrict__ wtl,
    const float* __restrict__ bias,
    ushort* __restrict__ s_out,
    const float* __restrict__ lin_w, const float* __restrict__ lin_b,
    float* __restrict__ out, int M)
{
    __shared__ __align__(16) ushort Ah[4][64][8];   // 4 KB
    __shared__ __align__(16) ushort Al[4][64][8];   // 4 KB
    __shared__ __align__(16) ushort Bh[4][128][8];  // 8 KB
    __shared__ __align__(16) ushort Bl[4][128][8];  // 8 KB

    const int t    = threadIdx.x;
    const int rb   = blockIdx.x * 64;
    const int wid  = t >> 6;
    const int wm   = wid >> 1;         // row half (32 rows)
    const int wn   = wid & 1;          // col half (64 cols)
    const int lane = t & 63;
    const int lr   = lane & 15;
    const int kg   = lane >> 4;

    f32x4 acc[2][4] = {};

    for (int ks = 0; ks < 8; ++ks) {
        const bool isAgg = (ks < 4);
        // ---- stage A: [4 kg][64 rows][8 bf16], 16 B per thread per plane ----
        {
            int row = t >> 2, kg2 = t & 3;
            int grow = rb + row;
            int kofs = (ks & 3) * 32 + kg2 * 8;
            uint4 vh = {0, 0, 0, 0}, vl = {0, 0, 0, 0};
            if (grow < M) {
                const ushort* ah = isAgg ? aggh : xh;
                vh = *(const uint4*)(ah + (size_t)grow * 128 + kofs);
                if (isAgg) vl = *(const uint4*)(aggl + (size_t)grow * 128 + kofs);
            }
            *(uint4*)&Ah[kg2][row][0] = vh;
            if (isAgg) *(uint4*)&Al[kg2][row][0] = vl;
        }
        // ---- stage B: 512 16B-chunks per plane, 2 chunks/thread/plane ----
        {
            size_t base = (size_t)ks * 512;
            uint4* bhf = (uint4*)&Bh[0][0][0];
            uint4* blf = (uint4*)&Bl[0][0][0];
            const uint4* sh = (const uint4*)wth + base;
            const uint4* sl = (const uint4*)wtl + base;
            bhf[t * 2 + 0] = sh[t * 2 + 0];
            bhf[t * 2 + 1] = sh[t * 2 + 1];
            blf[t * 2 + 0] = sl[t * 2 + 0];
            blf[t * 2 + 1] = sl[t * 2 + 1];
        }
        __syncthreads();
        // ---- fragments + MFMA ----
        bf16x8 a_h[2], a_l[2], b_h[4], b_l[4];
        #pragma unroll
        for (int mt = 0; mt < 2; ++mt) {
            int r = wm * 32 + mt * 16 + lr;
            a_h[mt] = *(const bf16x8*)&Ah[kg][r][0];
            a_l[mt] = isAgg ? *(const bf16x8*)&Al[kg][r][0] : a_h[mt];
        }
        #pragma unroll
        for (int nt = 0; nt < 4; ++nt) {
            int c = wn * 64 + nt * 16 + lr;
            b_h[nt] = *(const bf16x8*)&Bh[kg][c][0];
            b_l[nt] = *(const bf16x8*)&Bl[kg][c][0];
        }
        #pragma unroll
        for (int mt = 0; mt < 2; ++mt) {
            #pragma unroll
            for (int nt = 0; nt < 4; ++nt) {
                acc[mt][nt] = __builtin_amdgcn_mfma_f32_16x16x32_bf16(
                    a_h[mt], b_h[nt], acc[mt][nt], 0, 0, 0);
                acc[mt][nt] = __builtin_amdgcn_mfma_f32_16x16x32_bf16(
                    a_h[mt], b_l[nt], acc[mt][nt], 0, 0, 0);
                if (isAgg)
                    acc[mt][nt] = __builtin_amdgcn_mfma_f32_16x16x32_bf16(
                        a_l[mt], b_h[nt], acc[mt][nt], 0, 0, 0);
            }
        }
        __syncthreads();
    }

    // ---- epilogue ----
    #pragma unroll
    for (int mt = 0; mt < 2; ++mt) {
        #pragma unroll
        for (int r = 0; r < 4; ++r) {
            int grow = rb + wm * 32 + mt * 16 + kg * 4 + r;
            if constexpr (FINAL) {
                float p0 = 0.f, p1 = 0.f;
                #pragma unroll
                for (int nt = 0; nt < 4; ++nt) {
                    int col = wn * 64 + nt * 16 + lr;
                    float v = fmaxf(acc[mt][nt][r] + bias[col], 0.f);
                    float2 lw = *(const float2*)(lin_w + col * 2);
                    p0 += v * lw.x;
                    p1 += v * lw.y;
                }
                #pragma unroll
                for (int off = 1; off < 16; off <<= 1) {
                    p0 += __shfl_xor(p0, off);
                    p1 += __shfl_xor(p1, off);
                }
                if (lr == 0 && grow < M) {
                    float b0 = (wn == 0) ? lin_b[0] : 0.f;
                    float b1 = (wn == 0) ? lin_b[1] : 0.f;
                    atomicAdd(&out[(size_t)grow * 2 + 0], p0 + b0);
                    atomicAdd(&out[(size_t)grow * 2 + 1], p1 + b1);
                }
            } else {
                #pragma unroll
                for (int nt = 0; nt < 4; ++nt) {
                    int col = wn * 64 + nt * 16 + lr;
                    float v = fmaxf(acc[mt][nt][r] + bias[col], 0.f);
                    if (grow < M)
                        s_out[(size_t)grow * 128 + col] = f2bf(v);
                }
            }
        }
    }
}

// ---------------------------------------------------------------------------
extern "C" void kernel_launch(void* const* d_in, const int* in_sizes, int n_in,
                              void* d_out, int out_size, void* d_ws, size_t ws_size,
                              hipStream_t stream)
{
    const float* x_subject = (const float*)d_in[0];
    const float* w1l  = (const float*)d_in[6];
    const float* w1r  = (const float*)d_in[7];
    const float* w2l  = (const float*)d_in[12];
    const float* w2r  = (const float*)d_in[13];
    const float* b1   = (const float*)d_in[16];
    const float* b2   = (const float*)d_in[19];
    const float* linw = (const float*)d_in[20];
    const float* linb = (const float*)d_in[21];
    const int* ss_src = (const int*)d_in[26];
    const int* ss_dst = (const int*)d_in[27];

    // Workspace layout (~55.5 MB; re-poisoned 0xAA each call):
    char* wp = (char*)d_ws;
    ushort* xh   = (ushort*)wp; wp += (size_t)NS * D * 2;   // 12.8 MB
    ushort* s1h  = (ushort*)wp; wp += (size_t)NS * D * 2;   // 12.8 MB
    ushort* aggh = (ushort*)wp; wp += (size_t)NS * D * 2;   // 12.8 MB
    ushort* aggl = (ushort*)wp; wp += (size_t)NS * D * 2;   // 12.8 MB
    ushort* wt1h = (ushort*)wp; wp += 256 * 128 * 2;        // 64 KB
    ushort* wt1l = (ushort*)wp; wp += 256 * 128 * 2;
    ushort* wt2h = (ushort*)wp; wp += 256 * 128 * 2;
    ushort* wt2l = (ushort*)wp; wp += 256 * 128 * 2;
    int* deg       = (int*)wp; wp += NS * 4;
    int* row_start = (int*)wp; wp += NS * 4;
    int* pos       = (int*)wp; wp += NS * 4;
    int* esrc      = (int*)wp; wp += (size_t)ESS * 4;       // 3.2 MB
    int* bsum      = (int*)wp; wp += SCAN_BLOCKS * 4;
    int* boff      = (int*)wp; wp += SCAN_BLOCKS * 4;

    const int edge_blocks = (ESS + 255) / 256;   // 3125
    const int gath_blocks = (NS + 3) / 4;        // 12500
    const int gemm_blocks = (NS + 63) / 64;      // 782

    // ---- zero init (deg for CSR, d_out for the fused-projection atomics) ----
    hipMemsetAsync(deg, 0, NS * sizeof(int), stream);
    hipMemsetAsync(d_out, 0, (size_t)NS * 2 * sizeof(float), stream);

    // ---- precompute bf16 planes ----
    split_x_k<<<(NS * D / 8 + 255) / 256, 256, 0, stream>>>(x_subject, xh, NS * D / 8);
    prep_w_k<<<256, 256, 0, stream>>>(w1l, w1r, w2l, w2r, wt1h, wt1l, wt2h, wt2l);

    // ---- CSR build (edge list shared by both layers) ----
    count_deg_k<<<edge_blocks, 256, 0, stream>>>(ss_dst, deg, ESS);
    block_sum_k<<<SCAN_BLOCKS, 256, 0, stream>>>(deg, bsum, NS);
    scan_partials_k<<<1, 256, 0, stream>>>(bsum, boff, SCAN_BLOCKS);
    scan_final_k<<<SCAN_BLOCKS, 256, 0, stream>>>(deg, boff, row_start, pos, NS);
    fill_csr_k<<<edge_blocks, 256, 0, stream>>>(ss_src, ss_dst, pos, esrc, ESS);

    // ---- Layer 1 (roi branch is dead code w.r.t. the output) ----
    gather_mean_bf16_k<<<gath_blocks, 256, 0, stream>>>(xh, esrc, row_start,
                                                        deg, aggh, aggl, NS);
    sage_mfma_k<false><<<gemm_blocks, 256, 0, stream>>>(
        aggh, aggl, xh, wt1h, wt1l, b1, s1h, nullptr, nullptr, nullptr, NS);

    // ---- Layer 2 (same CSR) ----
    gather_mean_bf16_k<<<gath_blocks, 256, 0, stream>>>(s1h, esrc, row_start,
                                                        deg, aggh, aggl, NS);
    sage_mfma_k<true><<<gemm_blocks, 256, 0, stream>>>(
        aggh, aggl, s1h, wt2h, wt2l, b2, nullptr, linw, linb, (float*)d_out, NS);
}

// Round 6
// 314.441 us; speedup vs baseline: 9.5347x; 1.1407x over previous
//
#include <hip/hip_runtime.h>

// Problem constants (match reference)
#define NS   50000
#define ESS  800000
#define D    128

// Bucketed counting-sort parameters
#define BSPAN 256                         // dst nodes per bucket
#define NB    ((NS + BSPAN - 1) / BSPAN)  // 196 buckets
#define EPB   4096                        // edges per hist/scatter block
#define NBLK  ((ESS + EPB - 1) / EPB)     // 196 blocks
#define NHIST (NB * NBLK)                 // 38416
#define SCAN2_BLOCKS ((NHIST + 255) / 256) // 151

typedef __attribute__((ext_vector_type(8))) short bf16x8;
typedef __attribute__((ext_vector_type(4))) float f32x4;

// f32 -> bf16 round-to-nearest-even (bits)
static __device__ __forceinline__ ushort f2bf(float f) {
    uint u = __float_as_uint(f);
    u += 0x7fffu + ((u >> 16) & 1u);
    return (ushort)(u >> 16);
}
static __device__ __forceinline__ float bf2f(ushort h) {
    return __uint_as_float((uint)h << 16);
}

// ---------------------------------------------------------------------------
// Split x_subject (f32) -> bf16 hi plane. 8 elems/thread.
// ---------------------------------------------------------------------------
__global__ __launch_bounds__(256) void split_x_k(
    const float* __restrict__ x, ushort* __restrict__ xh, int n8)
{
    int i = blockIdx.x * 256 + threadIdx.x;
    if (i >= n8) return;
    const float4* src = (const float4*)(x + (size_t)i * 8);
    float4 a = src[0], b = src[1];
    uint4 o;
    o.x = (uint)f2bf(a.x) | ((uint)f2bf(a.y) << 16);
    o.y = (uint)f2bf(a.z) | ((uint)f2bf(a.w) << 16);
    o.z = (uint)f2bf(b.x) | ((uint)f2bf(b.y) << 16);
    o.w = (uint)f2bf(b.z) | ((uint)f2bf(b.w) << 16);
    *(uint4*)(xh + (size_t)i * 8) = o;
}

// ---------------------------------------------------------------------------
// Prep W: combined [Wl;Wr] (256x128 f32) -> hi/lo bf16 planes in the MFMA
// fragment layout: elem index = ((k>>5)*4 + ((k>>3)&3))*128*8 + col*8 + (k&7).
// Covers both layers (layer = tid >> 15).
// ---------------------------------------------------------------------------
__global__ __launch_bounds__(256) void prep_w_k(
    const float* __restrict__ w1l, const float* __restrict__ w1r,
    const float* __restrict__ w2l, const float* __restrict__ w2r,
    ushort* __restrict__ wt1h, ushort* __restrict__ wt1l,
    ushort* __restrict__ wt2h, ushort* __restrict__ wt2l)
{
    int t = blockIdx.x * 256 + threadIdx.x;   // 0 .. 65535
    int layer = t >> 15;
    int rem   = t & 32767;
    int k     = rem >> 7;
    int col   = rem & 127;
    const float* wl = layer ? w2l : w1l;
    const float* wr = layer ? w2r : w1r;
    float v = (k < 128) ? wl[k * 128 + col] : wr[(k - 128) * 128 + col];
    ushort h = f2bf(v);
    ushort l = f2bf(v - bf2f(h));
    size_t idx = ((size_t)((k >> 5) * 4 + ((k >> 3) & 3)) * 128 + col) * 8 + (k & 7);
    ushort* dh = layer ? wt2h : wt1h;
    ushort* dl = layer ? wt2l : wt1l;
    dh[idx] = h;
    dl[idx] = l;
}

// ---------------------------------------------------------------------------
// CSR build, LDS-only counting sort. Step 1: per-block histogram over NB
// dst-buckets -> blockhist[bucket][block]. No global atomics.
// ---------------------------------------------------------------------------
__global__ __launch_bounds__(256) void hist_k(
    const int* __restrict__ dst, int* __restrict__ blockhist)
{
    __shared__ int lh[NB];
    int t = threadIdx.x, blk = blockIdx.x;
    if (t < NB) lh[t] = 0;
    __syncthreads();
    #pragma unroll
    for (int i = 0; i < EPB / 256; ++i) {
        int e = blk * EPB + i * 256 + t;
        if (e < ESS) atomicAdd(&lh[dst[e] >> 8], 1);
    }
    __syncthreads();
    if (t < NB) blockhist[t * NBLK + blk] = lh[t];
}

// ---------------------------------------------------------------------------
// Hierarchical scan (generic, reused from R4) over blockhist -> shist
// (exclusive prefix in bucket-major order = staging offsets).
// ---------------------------------------------------------------------------
__global__ __launch_bounds__(256) void block_sum_k(
    const int* __restrict__ deg, int* __restrict__ bsum, int n)
{
    __shared__ int lds[256];
    int i = blockIdx.x * 256 + threadIdx.x;
    int v = (i < n) ? deg[i] : 0;
    lds[threadIdx.x] = v;
    __syncthreads();
    for (int off = 128; off > 0; off >>= 1) {
        if (threadIdx.x < off) lds[threadIdx.x] += lds[threadIdx.x + off];
        __syncthreads();
    }
    if (threadIdx.x == 0) bsum[blockIdx.x] = lds[0];
}

__global__ __launch_bounds__(256) void scan_partials_k(
    const int* __restrict__ bsum, int* __restrict__ boff, int nb)
{
    __shared__ int lds[256];
    int t = threadIdx.x;
    int v = (t < nb) ? bsum[t] : 0;
    lds[t] = v;
    __syncthreads();
    for (int off = 1; off < 256; off <<= 1) {
        int other = (t >= off) ? lds[t - off] : 0;
        __syncthreads();
        lds[t] += other;
        __syncthreads();
    }
    if (t < nb) boff[t] = lds[t] - v;
}

__global__ __launch_bounds__(256) void scan_final_k(
    const int* __restrict__ deg, const int* __restrict__ boff,
    int* __restrict__ row_start, int n)
{
    __shared__ int lds[256];
    int t = threadIdx.x;
    int i = blockIdx.x * 256 + t;
    int v = (i < n) ? deg[i] : 0;
    lds[t] = v;
    __syncthreads();
    for (int off = 1; off < 256; off <<= 1) {
        int other = (t >= off) ? lds[t - off] : 0;
        __syncthreads();
        lds[t] += other;
        __syncthreads();
    }
    if (i < n) row_start[i] = boff[blockIdx.x] + lds[t] - v;
}

// ---------------------------------------------------------------------------
// Step 3: scatter edges into bucket-major staging via LDS cursors
// (deterministic per-(bucket,block) bases from shist). Writes within each
// bucket fill sequential slots -> lines coalesce in L2, no amplification.
// Pack: src (16 bits, NS<65536) | dstlocal (8 bits) << 16.
// ---------------------------------------------------------------------------
__global__ __launch_bounds__(256) void scatter_pairs_k(
    const int* __restrict__ src, const int* __restrict__ dst,
    const int* __restrict__ shist, uint* __restrict__ staging)
{
    __shared__ int lcur[NB];
    int t = threadIdx.x, blk = blockIdx.x;
    if (t < NB) lcur[t] = shist[t * NBLK + blk];
    __syncthreads();
    #pragma unroll
    for (int i = 0; i < EPB / 256; ++i) {
        int e = blk * EPB + i * 256 + t;
        if (e < ESS) {
            int d = dst[e];
            int slot = atomicAdd(&lcur[d >> 8], 1);
            staging[slot] = (uint)src[e] | ((uint)(d & 255) << 16);
        }
    }
}

// ---------------------------------------------------------------------------
// Step 4: one block per bucket. LDS histogram -> deg, LDS scan -> row_start,
// LDS cursors -> final esrc placement. All scattered writes land in the
// bucket's ~16 KB esrc window (L2-hot). No global atomics.
// ---------------------------------------------------------------------------
__global__ __launch_bounds__(256) void bucket_csr_k(
    const uint* __restrict__ staging, const int* __restrict__ shist,
    int* __restrict__ deg, int* __restrict__ row_start,
    int* __restrict__ esrc)
{
    __shared__ int ldeg[BSPAN], lscan[BSPAN], lcur[BSPAN];
    int b = blockIdx.x, t = threadIdx.x;
    int base = shist[b * NBLK];
    int next = (b == NB - 1) ? ESS : shist[(b + 1) * NBLK];
    int n = next - base;
    ldeg[t] = 0;
    __syncthreads();
    for (int i = t; i < n; i += 256)
        atomicAdd(&ldeg[staging[base + i] >> 16], 1);
    __syncthreads();
    int v = ldeg[t];
    lscan[t] = v;
    __syncthreads();
    for (int off = 1; off < 256; off <<= 1) {
        int o = (t >= off) ? lscan[t - off] : 0;
        __syncthreads();
        lscan[t] += o;
        __syncthreads();
    }
    int excl = lscan[t] - v;
    int node = b * BSPAN + t;
    if (node < NS) {
        deg[node] = v;
        row_start[node] = base + excl;
    }
    lcur[t] = base + excl;
    __syncthreads();
    for (int i = t; i < n; i += 256) {
        uint p = staging[base + i];
        int slot = atomicAdd(&lcur[p >> 16], 1);
        esrc[slot] = (int)(p & 0xffffu);
    }
}

// ---------------------------------------------------------------------------
// Gather-mean over bf16 rows: one wave per dst node, lane owns 2 bf16 (1 u32).
// Edge loop unrolled x8 with independent accumulators (MLP). Accumulate f32,
// write agg as hi/lo bf16 planes.
// ---------------------------------------------------------------------------
__global__ __launch_bounds__(256) void gather_mean_bf16_k(
    const ushort* __restrict__ xh, const int* __restrict__ esrc,
    const int* __restrict__ row_start, const int* __restrict__ deg,
    ushort* __restrict__ aggh, ushort* __restrict__ aggl, int M)
{
    int d = blockIdx.x * 4 + (threadIdx.x >> 6);
    if (d >= M) return;
    int lane = threadIdx.x & 63;
    int beg = row_start[d];
    int n   = deg[d];
    const uint* xp = reinterpret_cast<const uint*>(xh);
    float sx[8] = {}, sy[8] = {};
    int j = 0;
    for (; j + 7 < n; j += 8) {
        uint u[8];
        #pragma unroll
        for (int q = 0; q < 8; ++q) {
            int s = esrc[beg + j + q];
            u[q] = xp[(size_t)s * 64 + lane];
        }
        #pragma unroll
        for (int q = 0; q < 8; ++q) {
            sx[q] += __uint_as_float(u[q] << 16);
            sy[q] += __uint_as_float(u[q] & 0xffff0000u);
        }
    }
    for (; j < n; ++j) {
        int s = esrc[beg + j];
        uint u = xp[(size_t)s * 64 + lane];
        sx[0] += __uint_as_float(u << 16);
        sy[0] += __uint_as_float(u & 0xffff0000u);
    }
    float ax = ((sx[0] + sx[1]) + (sx[2] + sx[3])) + ((sx[4] + sx[5]) + (sx[6] + sx[7]));
    float ay = ((sy[0] + sy[1]) + (sy[2] + sy[3])) + ((sy[4] + sy[5]) + (sy[6] + sy[7]));
    float scale = 1.0f / fmaxf((float)n, 1.0f);
    ax *= scale; ay *= scale;
    ushort hx = f2bf(ax), hy = f2bf(ay);
    ushort lx = f2bf(ax - bf2f(hx)), ly = f2bf(ay - bf2f(hy));
    reinterpret_cast<uint*>(aggh)[(size_t)d * 64 + lane] = (uint)hx | ((uint)hy << 16);
    reinterpret_cast<uint*>(aggl)[(size_t)d * 64 + lane] = (uint)lx | ((uint)ly << 16);
}

// ---------------------------------------------------------------------------
// MFMA SAGE linear v2. out_row = relu([agg | x] @ [Wl;Wr] + bias).
// agg half: split-bf16 compensation (Ah*Bh + Ah*Bl + Al*Bh); x half hi-only A.
// v2: ALL of A staged to LDS once (48 KB, ONE barrier); B fragments read
// directly from global (wt* is 128 KB, L2-hot, already in fragment layout).
// Block: 256 thr = 4 waves (2x2), tile 64 rows x 128 cols, K=256 in 8 steps.
// mfma_f32_16x16x32_bf16: A row=lane&15, k=(lane>>4)*8+e; B col=lane&15;
// D col=lane&15, row=(lane>>4)*4+reg (m89-verified).
// ---------------------------------------------------------------------------
template<bool FINAL>
__global__ __launch_bounds__(256) void sage_mfma_k(
    const ushort* __restrict__ aggh, const ushort* __restrict__ aggl,
    const ushort* __restrict__ xh,
    const ushort* __restrict__ wth, const ushort* __restrict__ wtl,
    const float* __restrict__ bias,
    ushort* __restrict__ s_out,
    const float* __restrict__ lin_w, const float* __restrict__ lin_b,
    float* __restrict__ out, int M)
{
    __shared__ __align__(16) ushort Ahs[8][4][64][8];   // 32 KB: agg+x hi
    __shared__ __align__(16) ushort Als[4][4][64][8];   // 16 KB: agg lo

    const int t    = threadIdx.x;
    const int rb   = blockIdx.x * 64;
    const int wid  = t >> 6;
    const int wm   = wid >> 1;         // row half (32 rows)
    const int wn   = wid & 1;          // col half (64 cols)
    const int lane = t & 63;
    const int lr   = lane & 15;
    const int kg   = lane >> 4;

    // ---- stage ALL of A: thread t loads row t>>2, k-chunk (t&3) per ks ----
    {
        int row = t >> 2, q = t & 3;
        int grow = rb + row;
        bool ok = grow < M;
        #pragma unroll
        for (int i = 0; i < 8; ++i) {
            const ushort* sp = (i < 4)
                ? aggh + (size_t)grow * 128 + i * 32 + q * 8
                : xh   + (size_t)grow * 128 + (i - 4) * 32 + q * 8;
            uint4 v = make_uint4(0, 0, 0, 0);
            if (ok) v = *(const uint4*)sp;
            *(uint4*)&Ahs[i][q][row][0] = v;
        }
        #pragma unroll
        for (int i = 0; i < 4; ++i) {
            const ushort* sp = aggl + (size_t)grow * 128 + i * 32 + q * 8;
            uint4 v = make_uint4(0, 0, 0, 0);
            if (ok) v = *(const uint4*)sp;
            *(uint4*)&Als[i][q][row][0] = v;
        }
    }
    __syncthreads();

    f32x4 acc[2][4] = {};
    #pragma unroll
    for (int ks = 0; ks < 8; ++ks) {
        const bool isAgg = (ks < 4);
        bf16x8 ah[2], al[2], bh[4], bl[4];
        #pragma unroll
        for (int nt = 0; nt < 4; ++nt) {
            int c = wn * 64 + nt * 16 + lr;
            size_t off = ((size_t)(ks * 4 + kg) * 128 + c) * 8;
            bh[nt] = *(const bf16x8*)(wth + off);
            bl[nt] = *(const bf16x8*)(wtl + off);
        }
        #pragma unroll
        for (int mt = 0; mt < 2; ++mt) {
            int r = wm * 32 + mt * 16 + lr;
            ah[mt] = *(const bf16x8*)&Ahs[ks][kg][r][0];
            al[mt] = isAgg ? *(const bf16x8*)&Als[ks][kg][r][0] : ah[mt];
        }
        #pragma unroll
        for (int mt = 0; mt < 2; ++mt) {
            #pragma unroll
            for (int nt = 0; nt < 4; ++nt) {
                acc[mt][nt] = __builtin_amdgcn_mfma_f32_16x16x32_bf16(
                    ah[mt], bh[nt], acc[mt][nt], 0, 0, 0);
                acc[mt][nt] = __builtin_amdgcn_mfma_f32_16x16x32_bf16(
                    ah[mt], bl[nt], acc[mt][nt], 0, 0, 0);
                if (isAgg)
                    acc[mt][nt] = __builtin_amdgcn_mfma_f32_16x16x32_bf16(
                        al[mt], bh[nt], acc[mt][nt], 0, 0, 0);
            }
        }
    }

    // ---- epilogue ----
    #pragma unroll
    for (int mt = 0; mt < 2; ++mt) {
        #pragma unroll
        for (int r = 0; r < 4; ++r) {
            int grow = rb + wm * 32 + mt * 16 + kg * 4 + r;
            if constexpr (FINAL) {
                float p0 = 0.f, p1 = 0.f;
                #pragma unroll
                for (int nt = 0; nt < 4; ++nt) {
                    int col = wn * 64 + nt * 16 + lr;
                    float v = fmaxf(acc[mt][nt][r] + bias[col], 0.f);
                    float2 lw = *(const float2*)(lin_w + col * 2);
                    p0 += v * lw.x;
                    p1 += v * lw.y;
                }
                #pragma unroll
                for (int off = 1; off < 16; off <<= 1) {
                    p0 += __shfl_xor(p0, off);
                    p1 += __shfl_xor(p1, off);
                }
                if (lr == 0 && grow < M) {
                    float b0 = (wn == 0) ? lin_b[0] : 0.f;
                    float b1 = (wn == 0) ? lin_b[1] : 0.f;
                    atomicAdd(&out[(size_t)grow * 2 + 0], p0 + b0);
                    atomicAdd(&out[(size_t)grow * 2 + 1], p1 + b1);
                }
            } else {
                #pragma unroll
                for (int nt = 0; nt < 4; ++nt) {
                    int col = wn * 64 + nt * 16 + lr;
                    float v = fmaxf(acc[mt][nt][r] + bias[col], 0.f);
                    if (grow < M)
                        s_out[(size_t)grow * 128 + col] = f2bf(v);
                }
            }
        }
    }
}

// ---------------------------------------------------------------------------
extern "C" void kernel_launch(void* const* d_in, const int* in_sizes, int n_in,
                              void* d_out, int out_size, void* d_ws, size_t ws_size,
                              hipStream_t stream)
{
    const float* x_subject = (const float*)d_in[0];
    const float* w1l  = (const float*)d_in[6];
    const float* w1r  = (const float*)d_in[7];
    const float* w2l  = (const float*)d_in[12];
    const float* w2r  = (const float*)d_in[13];
    const float* b1   = (const float*)d_in[16];
    const float* b2   = (const float*)d_in[19];
    const float* linw = (const float*)d_in[20];
    const float* linb = (const float*)d_in[21];
    const int* ss_src = (const int*)d_in[26];
    const int* ss_dst = (const int*)d_in[27];

    // Workspace layout (~58.5 MB; re-poisoned 0xAA each call):
    char* wp = (char*)d_ws;
    ushort* xh      = (ushort*)wp; wp += (size_t)NS * D * 2;   // 12.8 MB
    ushort* s1h     = (ushort*)wp; wp += (size_t)NS * D * 2;   // 12.8 MB
    ushort* aggh    = (ushort*)wp; wp += (size_t)NS * D * 2;   // 12.8 MB
    ushort* aggl    = (ushort*)wp; wp += (size_t)NS * D * 2;   // 12.8 MB
    ushort* wt1h    = (ushort*)wp; wp += 256 * 128 * 2;        // 64 KB
    ushort* wt1l    = (ushort*)wp; wp += 256 * 128 * 2;
    ushort* wt2h    = (ushort*)wp; wp += 256 * 128 * 2;
    ushort* wt2l    = (ushort*)wp; wp += 256 * 128 * 2;
    uint*  staging  = (uint*)wp;  wp += (size_t)ESS * 4;       // 3.2 MB
    int*   esrc     = (int*)wp;   wp += (size_t)ESS * 4;       // 3.2 MB
    int*   blockhist= (int*)wp;   wp += (size_t)NHIST * 4;     // 154 KB
    int*   shist    = (int*)wp;   wp += (size_t)NHIST * 4;     // 154 KB
    int*   deg      = (int*)wp;   wp += NS * 4;
    int*   row_start= (int*)wp;   wp += NS * 4;
    int*   bsum     = (int*)wp;   wp += 256 * 4;
    int*   boff     = (int*)wp;   wp += 256 * 4;

    const int gath_blocks = (NS + 3) / 4;        // 12500
    const int gemm_blocks = (NS + 63) / 64;      // 782

    // d_out zero (fused-projection atomics accumulate into it)
    hipMemsetAsync(d_out, 0, (size_t)NS * 2 * sizeof(float), stream);

    // ---- precompute bf16 planes ----
    split_x_k<<<(NS * D / 8 + 255) / 256, 256, 0, stream>>>(x_subject, xh, NS * D / 8);
    prep_w_k<<<256, 256, 0, stream>>>(w1l, w1r, w2l, w2r, wt1h, wt1l, wt2h, wt2l);

    // ---- CSR build: LDS-only counting sort (no global atomics) ----
    hist_k<<<NBLK, 256, 0, stream>>>(ss_dst, blockhist);
    block_sum_k<<<SCAN2_BLOCKS, 256, 0, stream>>>(blockhist, bsum, NHIST);
    scan_partials_k<<<1, 256, 0, stream>>>(bsum, boff, SCAN2_BLOCKS);
    scan_final_k<<<SCAN2_BLOCKS, 256, 0, stream>>>(blockhist, boff, shist, NHIST);
    scatter_pairs_k<<<NBLK, 256, 0, stream>>>(ss_src, ss_dst, shist, staging);
    bucket_csr_k<<<NB, 256, 0, stream>>>(staging, shist, deg, row_start, esrc);

    // ---- Layer 1 (roi branch is dead code w.r.t. the output) ----
    gather_mean_bf16_k<<<gath_blocks, 256, 0, stream>>>(xh, esrc, row_start,
                                                        deg, aggh, aggl, NS);
    sage_mfma_k<false><<<gemm_blocks, 256, 0, stream>>>(
        aggh, aggl, xh, wt1h, wt1l, b1, s1h, nullptr, nullptr, nullptr, NS);

    // ---- Layer 2 (same CSR) ----
    gather_mean_bf16_k<<<gath_blocks, 256, 0, stream>>>(s1h, esrc, row_start,
                                                        deg, aggh, aggl, NS);
    sage_mfma_k<true><<<gemm_blocks, 256, 0, stream>>>(
        aggh, aggl, s1h, wt2h, wt2l, b2, nullptr, linw, linb, (float*)d_out, NS);
}

// Round 7
// 311.142 us; speedup vs baseline: 9.6358x; 1.0106x over previous
//
#include <hip/hip_runtime.h>

// Problem constants (match reference)
#define NS   50000
#define ESS  800000
#define D    128

// Counting-sort parameters
#define BSPAN 256                         // dst nodes per bucket
#define NB    ((NS + BSPAN - 1) / BSPAN)  // 196 buckets
#define EPB   4096                        // edges per pack block (region size)
#define NBLK  ((ESS + EPB - 1) / EPB)     // 196 pack blocks
#define BCAP  8192                        // bucket edge capacity (Poisson(4096), 8192 = +64 sigma)

#define SPLIT_BLOCKS (NS * D / 8 / 256)   // 3125
#define PREP_BLOCKS  256

typedef __attribute__((ext_vector_type(8))) short bf16x8;
typedef __attribute__((ext_vector_type(4))) float f32x4;

// f32 -> bf16 round-to-nearest-even (bits)
static __device__ __forceinline__ ushort f2bf(float f) {
    uint u = __float_as_uint(f);
    u += 0x7fffu + ((u >> 16) & 1u);
    return (ushort)(u >> 16);
}
static __device__ __forceinline__ float bf2f(ushort h) {
    return __uint_as_float((uint)h << 16);
}

// ---------------------------------------------------------------------------
// Fused precompute: blocks [0,3125) split x->bf16; [3125,3381) transform W
// into MFMA fragment layout hi/lo planes; block 3381 zeroes btotal.
// W layout: elem index = ((k>>5)*4 + ((k>>3)&3))*128*8 + col*8 + (k&7).
// ---------------------------------------------------------------------------
__global__ __launch_bounds__(256) void splitprep_k(
    const float* __restrict__ x, ushort* __restrict__ xh,
    const float* __restrict__ w1l, const float* __restrict__ w1r,
    const float* __restrict__ w2l, const float* __restrict__ w2r,
    ushort* __restrict__ wt1h, ushort* __restrict__ wt1l,
    ushort* __restrict__ wt2h, ushort* __restrict__ wt2l,
    int* __restrict__ btotal)
{
    int blk = blockIdx.x, t = threadIdx.x;
    if (blk < SPLIT_BLOCKS) {
        int i = blk * 256 + t;                    // 8 floats per thread
        const float4* src = (const float4*)(x + (size_t)i * 8);
        float4 a = src[0], b = src[1];
        uint4 o;
        o.x = (uint)f2bf(a.x) | ((uint)f2bf(a.y) << 16);
        o.y = (uint)f2bf(a.z) | ((uint)f2bf(a.w) << 16);
        o.z = (uint)f2bf(b.x) | ((uint)f2bf(b.y) << 16);
        o.w = (uint)f2bf(b.z) | ((uint)f2bf(b.w) << 16);
        *(uint4*)(xh + (size_t)i * 8) = o;
    } else if (blk < SPLIT_BLOCKS + PREP_BLOCKS) {
        int g = (blk - SPLIT_BLOCKS) * 256 + t;   // 0..65535
        int layer = g >> 15;
        int rem   = g & 32767;
        int k     = rem >> 7;
        int col   = rem & 127;
        const float* wl = layer ? w2l : w1l;
        const float* wr = layer ? w2r : w1r;
        float v = (k < 128) ? wl[k * 128 + col] : wr[(k - 128) * 128 + col];
        ushort h = f2bf(v);
        ushort l = f2bf(v - bf2f(h));
        size_t idx = ((size_t)((k >> 5) * 4 + ((k >> 3) & 3)) * 128 + col) * 8 + (k & 7);
        (layer ? wt2h : wt1h)[idx] = h;
        (layer ? wt2l : wt1l)[idx] = l;
    } else {
        if (t < NB) btotal[t] = 0;
    }
}

// ---------------------------------------------------------------------------
// CSR step 1 (pack): each block owns edges [blk*EPB, ...) and staging region
// [blk*EPB, ...). Read edges once into LDS (packed src|dstlocal<<16|bucket<<24),
// LDS hist over buckets, LDS scan, scatter into OWN region grouped by bucket.
// Emits per-(blk,bucket) count+start and atomic bucket totals. No global
// scan needed; no scattered global writes.
// ---------------------------------------------------------------------------
__global__ __launch_bounds__(256) void pack_k(
    const int* __restrict__ src, const int* __restrict__ dst,
    uint* __restrict__ staging, int* __restrict__ blockhist,
    int* __restrict__ blockstart, int* __restrict__ btotal)
{
    __shared__ uint ldata[EPB];                    // 16 KB
    __shared__ int lh[256], lofs[256], lcur[256];
    int t = threadIdx.x, blk = blockIdx.x;
    int base = blk * EPB;
    int nmine = min(EPB, ESS - base);
    lh[t] = 0;
    __syncthreads();
    for (int i = t; i < nmine; i += 256) {
        int s = src[base + i], d = dst[base + i];
        ldata[i] = (uint)s | ((uint)(d & 255) << 16) | ((uint)(d >> 8) << 24);
        atomicAdd(&lh[d >> 8], 1);
    }
    __syncthreads();
    int v = lh[t];
    lofs[t] = v;
    __syncthreads();
    for (int off = 1; off < 256; off <<= 1) {
        int o = (t >= off) ? lofs[t - off] : 0;
        __syncthreads();
        lofs[t] += o;
        __syncthreads();
    }
    int excl = lofs[t] - v;
    if (t < NB) {
        blockhist[blk * NB + t]  = v;
        blockstart[blk * NB + t] = excl;
        if (v) atomicAdd(&btotal[t], v);
    }
    lcur[t] = excl;
    __syncthreads();
    for (int i = t; i < nmine; i += 256) {
        uint p = ldata[i];
        int slot = atomicAdd(&lcur[p >> 24], 1);
        staging[base + slot] = p;
    }
}

// ---------------------------------------------------------------------------
// CSR step 2: single tiny block scans the 196 bucket totals -> bucket_base.
// ---------------------------------------------------------------------------
__global__ __launch_bounds__(256) void scan196_k(
    const int* __restrict__ btotal, int* __restrict__ bucket_base)
{
    __shared__ int lds[256];
    int t = threadIdx.x;
    int v = (t < NB) ? btotal[t] : 0;
    lds[t] = v;
    __syncthreads();
    for (int off = 1; off < 256; off <<= 1) {
        int o = (t >= off) ? lds[t - off] : 0;
        __syncthreads();
        lds[t] += o;
        __syncthreads();
    }
    if (t < NB) bucket_base[t] = lds[t] - v;
}

// ---------------------------------------------------------------------------
// CSR step 3: one block per bucket. Thread t concatenates pack-block t's run
// for this bucket into LDS; then LDS hist over dstlocal -> deg, LDS scan ->
// row_start, LDS cursors -> esrc placement in the bucket's contiguous window.
// ---------------------------------------------------------------------------
__global__ __launch_bounds__(256) void bucket_csr_k(
    const uint* __restrict__ staging, const int* __restrict__ blockhist,
    const int* __restrict__ blockstart, const int* __restrict__ bucket_base,
    int* __restrict__ deg, int* __restrict__ row_start, int* __restrict__ esrc)
{
    __shared__ uint bdata[BCAP];                   // 32 KB
    __shared__ int lscan[256], ldeg[256], lcur[256];
    int b = blockIdx.x, t = threadIdx.x;
    // concat offsets: exclusive scan over pack-blocks' counts for bucket b
    int c = (t < NBLK) ? blockhist[t * NB + b] : 0;
    lscan[t] = c;
    __syncthreads();
    for (int off = 1; off < 256; off <<= 1) {
        int o = (t >= off) ? lscan[t - off] : 0;
        __syncthreads();
        lscan[t] += o;
        __syncthreads();
    }
    int total = min(lscan[255], BCAP);
    int excl  = lscan[t] - c;
    // copy this thread's run into LDS
    if (t < NBLK && c > 0) {
        const uint* sp = staging + (size_t)t * EPB + blockstart[t * NB + b];
        for (int i = 0; i < c; ++i)
            if (excl + i < BCAP) bdata[excl + i] = sp[i];
    }
    ldeg[t] = 0;
    __syncthreads();
    // hist over dst-local
    for (int i = t; i < total; i += 256)
        atomicAdd(&ldeg[(bdata[i] >> 16) & 255], 1);
    __syncthreads();
    int v = ldeg[t];
    lscan[t] = v;
    __syncthreads();
    for (int off = 1; off < 256; off <<= 1) {
        int o = (t >= off) ? lscan[t - off] : 0;
        __syncthreads();
        lscan[t] += o;
        __syncthreads();
    }
    int nexcl = lscan[t] - v;
    int gbase = bucket_base[b];
    int node  = b * BSPAN + t;
    if (node < NS) {
        deg[node] = v;
        row_start[node] = gbase + nexcl;
    }
    lcur[t] = nexcl;
    __syncthreads();
    for (int i = t; i < total; i += 256) {
        uint p = bdata[i];
        int slot = atomicAdd(&lcur[(p >> 16) & 255], 1);
        esrc[gbase + slot] = (int)(p & 0xffffu);
    }
}

// ---------------------------------------------------------------------------
// Gather-mean over bf16 rows: one wave per dst node, lane owns 2 bf16 (1 u32).
// Predicated unroll-8: tail iterations keep all 8 loads in flight (clamped
// index + mask) instead of a serial latency-chained remainder loop.
// ---------------------------------------------------------------------------
__global__ __launch_bounds__(256) void gather_mean_bf16_k(
    const ushort* __restrict__ xh, const int* __restrict__ esrc,
    const int* __restrict__ row_start, const int* __restrict__ deg,
    ushort* __restrict__ aggh, ushort* __restrict__ aggl, int M)
{
    int d = blockIdx.x * 4 + (threadIdx.x >> 6);
    if (d >= M) return;
    int lane = threadIdx.x & 63;
    int beg = row_start[d];
    int n   = deg[d];
    const uint* xp = reinterpret_cast<const uint*>(xh);
    float sx[8] = {}, sy[8] = {};
    for (int j = 0; j < n; j += 8) {
        uint u[8];
        bool m[8];
        #pragma unroll
        for (int q = 0; q < 8; ++q) {
            int jq = j + q;
            bool ok = jq < n;
            int s = esrc[beg + (ok ? jq : 0)];
            u[q] = xp[(size_t)s * 64 + lane];
            m[q] = ok;
        }
        #pragma unroll
        for (int q = 0; q < 8; ++q) {
            if (m[q]) {
                sx[q] += __uint_as_float(u[q] << 16);
                sy[q] += __uint_as_float(u[q] & 0xffff0000u);
            }
        }
    }
    float ax = ((sx[0] + sx[1]) + (sx[2] + sx[3])) + ((sx[4] + sx[5]) + (sx[6] + sx[7]));
    float ay = ((sy[0] + sy[1]) + (sy[2] + sy[3])) + ((sy[4] + sy[5]) + (sy[6] + sy[7]));
    float scale = 1.0f / fmaxf((float)n, 1.0f);
    ax *= scale; ay *= scale;
    ushort hx = f2bf(ax), hy = f2bf(ay);
    ushort lx = f2bf(ax - bf2f(hx)), ly = f2bf(ay - bf2f(hy));
    reinterpret_cast<uint*>(aggh)[(size_t)d * 64 + lane] = (uint)hx | ((uint)hy << 16);
    reinterpret_cast<uint*>(aggl)[(size_t)d * 64 + lane] = (uint)lx | ((uint)ly << 16);
}

// ---------------------------------------------------------------------------
// MFMA SAGE linear. out_row = relu([agg | x] @ [Wl;Wr] + bias).
// agg half: split-bf16 compensation (Ah*Bh + Ah*Bl + Al*Bh); x half hi-only A.
// A staged to LDS once (48 KB, one barrier); B fragments read from global
// (128 KB, L2-hot, pre-transformed to fragment layout).
// FINAL: fuse 128->2 projection; cross-wave combine via LDS (no atomics, no
// d_out pre-zero needed).
// mfma_f32_16x16x32_bf16: A row=lane&15, k=(lane>>4)*8+e; B col=lane&15;
// D col=lane&15, row=(lane>>4)*4+reg (m89-verified).
// ---------------------------------------------------------------------------
template<bool FINAL>
__global__ __launch_bounds__(256) void sage_mfma_k(
    const ushort* __restrict__ aggh, const ushort* __restrict__ aggl,
    const ushort* __restrict__ xh,
    const ushort* __restrict__ wth, const ushort* __restrict__ wtl,
    const float* __restrict__ bias,
    ushort* __restrict__ s_out,
    const float* __restrict__ lin_w, const float* __restrict__ lin_b,
    float* __restrict__ out, int M)
{
    __shared__ __align__(16) ushort Ahs[8][4][64][8];   // 32 KB: agg+x hi
    __shared__ __align__(16) ushort Als[4][4][64][8];   // 16 KB: agg lo
    __shared__ float lps[2][32][2];                     // FINAL combine

    const int t    = threadIdx.x;
    const int rb   = blockIdx.x * 64;
    const int wid  = t >> 6;
    const int wm   = wid >> 1;
    const int wn   = wid & 1;
    const int lane = t & 63;
    const int lr   = lane & 15;
    const int kg   = lane >> 4;

    {
        int row = t >> 2, q = t & 3;
        int grow = rb + row;
        bool ok = grow < M;
        #pragma unroll
        for (int i = 0; i < 8; ++i) {
            const ushort* sp = (i < 4)
                ? aggh + (size_t)grow * 128 + i * 32 + q * 8
                : xh   + (size_t)grow * 128 + (i - 4) * 32 + q * 8;
            uint4 v = make_uint4(0, 0, 0, 0);
            if (ok) v = *(const uint4*)sp;
            *(uint4*)&Ahs[i][q][row][0] = v;
        }
        #pragma unroll
        for (int i = 0; i < 4; ++i) {
            const ushort* sp = aggl + (size_t)grow * 128 + i * 32 + q * 8;
            uint4 v = make_uint4(0, 0, 0, 0);
            if (ok) v = *(const uint4*)sp;
            *(uint4*)&Als[i][q][row][0] = v;
        }
    }
    __syncthreads();

    f32x4 acc[2][4] = {};
    #pragma unroll
    for (int ks = 0; ks < 8; ++ks) {
        const bool isAgg = (ks < 4);
        bf16x8 ah[2], al[2], bh[4], bl[4];
        #pragma unroll
        for (int nt = 0; nt < 4; ++nt) {
            int c = wn * 64 + nt * 16 + lr;
            size_t off = ((size_t)(ks * 4 + kg) * 128 + c) * 8;
            bh[nt] = *(const bf16x8*)(wth + off);
            bl[nt] = *(const bf16x8*)(wtl + off);
        }
        #pragma unroll
        for (int mt = 0; mt < 2; ++mt) {
            int r = wm * 32 + mt * 16 + lr;
            ah[mt] = *(const bf16x8*)&Ahs[ks][kg][r][0];
            al[mt] = isAgg ? *(const bf16x8*)&Als[ks][kg][r][0] : ah[mt];
        }
        #pragma unroll
        for (int mt = 0; mt < 2; ++mt) {
            #pragma unroll
            for (int nt = 0; nt < 4; ++nt) {
                acc[mt][nt] = __builtin_amdgcn_mfma_f32_16x16x32_bf16(
                    ah[mt], bh[nt], acc[mt][nt], 0, 0, 0);
                acc[mt][nt] = __builtin_amdgcn_mfma_f32_16x16x32_bf16(
                    ah[mt], bl[nt], acc[mt][nt], 0, 0, 0);
                if (isAgg)
                    acc[mt][nt] = __builtin_amdgcn_mfma_f32_16x16x32_bf16(
                        al[mt], bh[nt], acc[mt][nt], 0, 0, 0);
            }
        }
    }

    if constexpr (FINAL) {
        float pv[2][4][2];
        #pragma unroll
        for (int mt = 0; mt < 2; ++mt) {
            #pragma unroll
            for (int r = 0; r < 4; ++r) {
                float p0 = 0.f, p1 = 0.f;
                #pragma unroll
                for (int nt = 0; nt < 4; ++nt) {
                    int col = wn * 64 + nt * 16 + lr;
                    float v = fmaxf(acc[mt][nt][r] + bias[col], 0.f);
                    float2 lw = *(const float2*)(lin_w + col * 2);
                    p0 += v * lw.x;
                    p1 += v * lw.y;
                }
                #pragma unroll
                for (int off = 1; off < 16; off <<= 1) {
                    p0 += __shfl_xor(p0, off);
                    p1 += __shfl_xor(p1, off);
                }
                pv[mt][r][0] = p0;
                pv[mt][r][1] = p1;
            }
        }
        if (wn == 1 && lr == 0) {
            #pragma unroll
            for (int mt = 0; mt < 2; ++mt)
                #pragma unroll
                for (int r = 0; r < 4; ++r) {
                    int row = mt * 16 + kg * 4 + r;
                    lps[wm][row][0] = pv[mt][r][0];
                    lps[wm][row][1] = pv[mt][r][1];
                }
        }
        __syncthreads();
        if (wn == 0 && lr == 0) {
            #pragma unroll
            for (int mt = 0; mt < 2; ++mt)
                #pragma unroll
                for (int r = 0; r < 4; ++r) {
                    int row = mt * 16 + kg * 4 + r;
                    int grow = rb + wm * 32 + row;
                    if (grow < M) {
                        out[(size_t)grow * 2 + 0] = pv[mt][r][0] + lps[wm][row][0] + lin_b[0];
                        out[(size_t)grow * 2 + 1] = pv[mt][r][1] + lps[wm][row][1] + lin_b[1];
                    }
                }
        }
    } else {
        #pragma unroll
        for (int mt = 0; mt < 2; ++mt) {
            #pragma unroll
            for (int r = 0; r < 4; ++r) {
                int grow = rb + wm * 32 + mt * 16 + kg * 4 + r;
                #pragma unroll
                for (int nt = 0; nt < 4; ++nt) {
                    int col = wn * 64 + nt * 16 + lr;
                    float v = fmaxf(acc[mt][nt][r] + bias[col], 0.f);
                    if (grow < M)
                        s_out[(size_t)grow * 128 + col] = f2bf(v);
                }
            }
        }
    }
}

// ---------------------------------------------------------------------------
extern "C" void kernel_launch(void* const* d_in, const int* in_sizes, int n_in,
                              void* d_out, int out_size, void* d_ws, size_t ws_size,
                              hipStream_t stream)
{
    const float* x_subject = (const float*)d_in[0];
    const float* w1l  = (const float*)d_in[6];
    const float* w1r  = (const float*)d_in[7];
    const float* w2l  = (const float*)d_in[12];
    const float* w2r  = (const float*)d_in[13];
    const float* b1   = (const float*)d_in[16];
    const float* b2   = (const float*)d_in[19];
    const float* linw = (const float*)d_in[20];
    const float* linb = (const float*)d_in[21];
    const int* ss_src = (const int*)d_in[26];
    const int* ss_dst = (const int*)d_in[27];

    // Workspace layout (~59 MB; re-poisoned 0xAA each call):
    char* wp = (char*)d_ws;
    ushort* xh        = (ushort*)wp; wp += (size_t)NS * D * 2;   // 12.8 MB
    ushort* s1h       = (ushort*)wp; wp += (size_t)NS * D * 2;   // 12.8 MB
    ushort* aggh      = (ushort*)wp; wp += (size_t)NS * D * 2;   // 12.8 MB
    ushort* aggl      = (ushort*)wp; wp += (size_t)NS * D * 2;   // 12.8 MB
    ushort* wt1h      = (ushort*)wp; wp += 256 * 128 * 2;        // 64 KB
    ushort* wt1l      = (ushort*)wp; wp += 256 * 128 * 2;
    ushort* wt2h      = (ushort*)wp; wp += 256 * 128 * 2;
    ushort* wt2l      = (ushort*)wp; wp += 256 * 128 * 2;
    uint*  staging    = (uint*)wp;  wp += (size_t)NBLK * EPB * 4; // 3.2 MB
    int*   esrc       = (int*)wp;   wp += (size_t)ESS * 4;        // 3.2 MB
    int*   blockhist  = (int*)wp;   wp += (size_t)NBLK * NB * 4;  // 154 KB
    int*   blockstart = (int*)wp;   wp += (size_t)NBLK * NB * 4;  // 154 KB
    int*   btotal     = (int*)wp;   wp += NB * 4;
    int*   bucket_base= (int*)wp;   wp += NB * 4;
    int*   deg        = (int*)wp;   wp += NS * 4;
    int*   row_start  = (int*)wp;   wp += NS * 4;

    const int gath_blocks = (NS + 3) / 4;        // 12500
    const int gemm_blocks = (NS + 63) / 64;      // 782

    // ---- precompute bf16 planes + zero btotal (1 fused launch) ----
    splitprep_k<<<SPLIT_BLOCKS + PREP_BLOCKS + 1, 256, 0, stream>>>(
        x_subject, xh, w1l, w1r, w2l, w2r, wt1h, wt1l, wt2h, wt2l, btotal);

    // ---- CSR build: 3 kernels, LDS-local, no global scan ----
    pack_k<<<NBLK, 256, 0, stream>>>(ss_src, ss_dst, staging,
                                     blockhist, blockstart, btotal);
    scan196_k<<<1, 256, 0, stream>>>(btotal, bucket_base);
    bucket_csr_k<<<NB, 256, 0, stream>>>(staging, blockhist, blockstart,
                                         bucket_base, deg, row_start, esrc);

    // ---- Layer 1 (roi branch is dead code w.r.t. the output) ----
    gather_mean_bf16_k<<<gath_blocks, 256, 0, stream>>>(xh, esrc, row_start,
                                                        deg, aggh, aggl, NS);
    sage_mfma_k<false><<<gemm_blocks, 256, 0, stream>>>(
        aggh, aggl, xh, wt1h, wt1l, b1, s1h, nullptr, nullptr, nullptr, NS);

    // ---- Layer 2 (same CSR) ----
    gather_mean_bf16_k<<<gath_blocks, 256, 0, stream>>>(s1h, esrc, row_start,
                                                        deg, aggh, aggl, NS);
    sage_mfma_k<true><<<gemm_blocks, 256, 0, stream>>>(
        aggh, aggl, s1h, wt2h, wt2l, b2, nullptr, linw, linb, (float*)d_out, NS);
}

// Round 9
// 293.328 us; speedup vs baseline: 10.2210x; 1.0607x over previous
//
#include <hip/hip_runtime.h>

// Problem constants (match reference)
#define NS   50000
#define ESS  800000
#define D    128

// Counting-sort parameters
#define BSPAN 256                         // dst nodes per bucket
#define NB    ((NS + BSPAN - 1) / BSPAN)  // 196 buckets
#define EPB   4096                        // edges per pack block (region size)
#define NBLK  ((ESS + EPB - 1) / EPB)     // 196 pack blocks
#define BCAP  8192                        // per-bucket esrc region (slots); padded max ~6.2K

#define SPLIT_BLOCKS (NS * D / 8 / 256)   // 3125
#define PREP_BLOCKS  256

typedef __attribute__((ext_vector_type(8))) short bf16x8;
typedef __attribute__((ext_vector_type(4))) float f32x4;

// f32 -> bf16 round-to-nearest-even (bits)
static __device__ __forceinline__ ushort f2bf(float f) {
    uint u = __float_as_uint(f);
    u += 0x7fffu + ((u >> 16) & 1u);
    return (ushort)(u >> 16);
}
static __device__ __forceinline__ float bf2f(ushort h) {
    return __uint_as_float((uint)h << 16);
}

// ---------------------------------------------------------------------------
// Fused precompute: blocks [0,3125) split x->bf16; [3125,3381) transform W
// into MFMA fragment layout hi/lo planes; last block zeroes the padding row
// (index NS) of xh and s1h (gather padding points there).
// W layout: elem index = ((k>>5)*4 + ((k>>3)&3))*128*8 + col*8 + (k&7).
// ---------------------------------------------------------------------------
__global__ __launch_bounds__(256) void splitprep_k(
    const float* __restrict__ x, ushort* __restrict__ xh,
    ushort* __restrict__ s1h,
    const float* __restrict__ w1l, const float* __restrict__ w1r,
    const float* __restrict__ w2l, const float* __restrict__ w2r,
    ushort* __restrict__ wt1h, ushort* __restrict__ wt1l,
    ushort* __restrict__ wt2h, ushort* __restrict__ wt2l)
{
    int blk = blockIdx.x, t = threadIdx.x;
    if (blk < SPLIT_BLOCKS) {
        int i = blk * 256 + t;                    // 8 floats per thread
        const float4* src = (const float4*)(x + (size_t)i * 8);
        float4 a = src[0], b = src[1];
        uint4 o;
        o.x = (uint)f2bf(a.x) | ((uint)f2bf(a.y) << 16);
        o.y = (uint)f2bf(a.z) | ((uint)f2bf(a.w) << 16);
        o.z = (uint)f2bf(b.x) | ((uint)f2bf(b.y) << 16);
        o.w = (uint)f2bf(b.z) | ((uint)f2bf(b.w) << 16);
        *(uint4*)(xh + (size_t)i * 8) = o;
    } else if (blk < SPLIT_BLOCKS + PREP_BLOCKS) {
        int g = (blk - SPLIT_BLOCKS) * 256 + t;   // 0..65535
        int layer = g >> 15;
        int rem   = g & 32767;
        int k     = rem >> 7;
        int col   = rem & 127;
        const float* wl = layer ? w2l : w1l;
        const float* wr = layer ? w2r : w1r;
        float v = (k < 128) ? wl[k * 128 + col] : wr[(k - 128) * 128 + col];
        ushort h = f2bf(v);
        ushort l = f2bf(v - bf2f(h));
        size_t idx = ((size_t)((k >> 5) * 4 + ((k >> 3) & 3)) * 128 + col) * 8 + (k & 7);
        (layer ? wt2h : wt1h)[idx] = h;
        (layer ? wt2l : wt1l)[idx] = l;
    } else {
        // zero padding row NS of xh and s1h (64 u32 each)
        if (t < 64)        ((uint*)(xh + (size_t)NS * D))[t] = 0u;
        else if (t < 128)  ((uint*)(s1h + (size_t)NS * D))[t - 64] = 0u;
    }
}

// ---------------------------------------------------------------------------
// CSR step 1 (pack): each block owns edges [blk*EPB, ...) and staging region
// [blk*EPB, ...). Read edges once into LDS (packed src|dstlocal<<16|bucket<<24),
// LDS hist over buckets, LDS scan, scatter into OWN region grouped by bucket.
// Emits per-(blk,bucket) count + start. No global atomics, no global scan.
// ---------------------------------------------------------------------------
__global__ __launch_bounds__(256) void pack_k(
    const int* __restrict__ src, const int* __restrict__ dst,
    uint* __restrict__ staging, int* __restrict__ blockhist,
    int* __restrict__ blockstart)
{
    __shared__ uint ldata[EPB];                    // 16 KB
    __shared__ int lh[256], lofs[256], lcur[256];
    int t = threadIdx.x, blk = blockIdx.x;
    int base = blk * EPB;
    int nmine = min(EPB, ESS - base);
    lh[t] = 0;
    __syncthreads();
    for (int i = t; i < nmine; i += 256) {
        int s = src[base + i], d = dst[base + i];
        ldata[i] = (uint)s | ((uint)(d & 255) << 16) | ((uint)(d >> 8) << 24);
        atomicAdd(&lh[d >> 8], 1);
    }
    __syncthreads();
    int v = lh[t];
    lofs[t] = v;
    __syncthreads();
    for (int off = 1; off < 256; off <<= 1) {
        int o = (t >= off) ? lofs[t - off] : 0;
        __syncthreads();
        lofs[t] += o;
        __syncthreads();
    }
    int excl = lofs[t] - v;
    if (t < NB) {
        blockhist[blk * NB + t]  = v;
        blockstart[blk * NB + t] = excl;
    }
    lcur[t] = excl;
    __syncthreads();
    for (int i = t; i < nmine; i += 256) {
        uint p = ldata[i];
        int slot = atomicAdd(&lcur[p >> 24], 1);
        staging[base + slot] = p;
    }
}

// ---------------------------------------------------------------------------
// CSR step 2: one block per bucket, fixed esrc region [b*BCAP, (b+1)*BCAP).
// Concat pack-block runs into LDS, hist over dstlocal -> deg, scan over
// PADDED counts ((deg+7)&~7) -> row_start, place pre-scaled byte offsets
// (src<<8), fill padding slots with the zero-row offset (NS<<8).
// ---------------------------------------------------------------------------
__global__ __launch_bounds__(256) void bucket_csr_k(
    const uint* __restrict__ staging, const int* __restrict__ blockhist,
    const int* __restrict__ blockstart,
    int* __restrict__ deg, int* __restrict__ row_start, uint* __restrict__ esrc)
{
    __shared__ uint bdata[BCAP];                   // 32 KB
    __shared__ int lscan[256], ldeg[256], lcur[256];
    int b = blockIdx.x, t = threadIdx.x;
    // concat offsets: exclusive scan over pack-blocks' counts for bucket b
    int c = (t < NBLK) ? blockhist[t * NB + b] : 0;
    lscan[t] = c;
    __syncthreads();
    for (int off = 1; off < 256; off <<= 1) {
        int o = (t >= off) ? lscan[t - off] : 0;
        __syncthreads();
        lscan[t] += o;
        __syncthreads();
    }
    int total = min(lscan[255], BCAP);
    int excl  = lscan[t] - c;
    if (t < NBLK && c > 0) {
        const uint* sp = staging + (size_t)t * EPB + blockstart[t * NB + b];
        for (int i = 0; i < c; ++i)
            if (excl + i < BCAP) bdata[excl + i] = sp[i];
    }
    ldeg[t] = 0;
    __syncthreads();
    for (int i = t; i < total; i += 256)
        atomicAdd(&ldeg[(bdata[i] >> 16) & 255], 1);
    __syncthreads();
    int v  = ldeg[t];
    int pv = (v + 7) & ~7;          // padded to multiple of 8
    lscan[t] = pv;
    __syncthreads();
    for (int off = 1; off < 256; off <<= 1) {
        int o = (t >= off) ? lscan[t - off] : 0;
        __syncthreads();
        lscan[t] += o;
        __syncthreads();
    }
    int pexcl = lscan[t] - pv;
    int gbase = b * BCAP;
    int node  = b * BSPAN + t;
    if (node < NS) {
        deg[node] = v;
        row_start[node] = gbase + pexcl;
    }
    lcur[t] = pexcl;
    __syncthreads();
    for (int i = t; i < total; i += 256) {
        uint p = bdata[i];
        int slot = atomicAdd(&lcur[(p >> 16) & 255], 1);
        esrc[gbase + slot] = (p & 0xffffu) << 8;   // pre-scaled byte offset
    }
    // padding slots [pexcl+v, pexcl+pv) -> zero-row offset (disjoint, no sync)
    for (int i = v; i < pv; ++i)
        esrc[gbase + pexcl + i] = (uint)NS << 8;
}

// ---------------------------------------------------------------------------
// Gather-mean over bf16 rows: one wave per dst node, lane owns 2 bf16 (1 u32).
// Edge lists padded to x8 with zero-row offsets: clean unroll-8, no masks.
// esrc holds pre-scaled byte offsets; indices loaded as uint4 pairs.
// ---------------------------------------------------------------------------
__global__ __launch_bounds__(256) void gather_mean_bf16_k(
    const ushort* __restrict__ xh, const uint* __restrict__ esrc,
    const int* __restrict__ row_start, const int* __restrict__ deg,
    ushort* __restrict__ aggh, ushort* __restrict__ aggl, int M)
{
    int d = blockIdx.x * 4 + (threadIdx.x >> 6);
    if (d >= M) return;
    int lane = threadIdx.x & 63;
    int beg = row_start[d];
    int n   = deg[d];
    int pn8 = (n + 7) >> 3;         // padded iterations
    const char* base = (const char*)xh;
    uint laneoff = (uint)lane << 2;
    const uint4* ip = (const uint4*)(esrc + beg);   // 16B-aligned (beg % 8 == 0)
    float sx[8] = {}, sy[8] = {};
    for (int j = 0; j < pn8; ++j) {
        uint4 o0 = ip[j * 2 + 0];
        uint4 o1 = ip[j * 2 + 1];
        uint u[8];
        u[0] = *(const uint*)(base + (o0.x + laneoff));
        u[1] = *(const uint*)(base + (o0.y + laneoff));
        u[2] = *(const uint*)(base + (o0.z + laneoff));
        u[3] = *(const uint*)(base + (o0.w + laneoff));
        u[4] = *(const uint*)(base + (o1.x + laneoff));
        u[5] = *(const uint*)(base + (o1.y + laneoff));
        u[6] = *(const uint*)(base + (o1.z + laneoff));
        u[7] = *(const uint*)(base + (o1.w + laneoff));
        #pragma unroll
        for (int q = 0; q < 8; ++q) {
            sx[q] += __uint_as_float(u[q] << 16);
            sy[q] += __uint_as_float(u[q] & 0xffff0000u);
        }
    }
    float ax = ((sx[0] + sx[1]) + (sx[2] + sx[3])) + ((sx[4] + sx[5]) + (sx[6] + sx[7]));
    float ay = ((sy[0] + sy[1]) + (sy[2] + sy[3])) + ((sy[4] + sy[5]) + (sy[6] + sy[7]));
    float scale = 1.0f / fmaxf((float)n, 1.0f);
    ax *= scale; ay *= scale;
    ushort hx = f2bf(ax), hy = f2bf(ay);
    ushort lx = f2bf(ax - bf2f(hx)), ly = f2bf(ay - bf2f(hy));
    reinterpret_cast<uint*>(aggh)[(size_t)d * 64 + lane] = (uint)hx | ((uint)hy << 16);
    reinterpret_cast<uint*>(aggl)[(size_t)d * 64 + lane] = (uint)lx | ((uint)ly << 16);
}

// ---------------------------------------------------------------------------
// MFMA SAGE linear. out_row = relu([agg | x] @ [Wl;Wr] + bias).
// agg half: split-bf16 compensation (Ah*Bh + Ah*Bl + Al*Bh); x half hi-only A.
// A staged to LDS once (48 KB, one barrier); B fragments read from global
// (128 KB, L2-hot, pre-transformed to fragment layout).
// FINAL: fuse 128->2 projection; cross-wave combine via LDS (no atomics).
// mfma_f32_16x16x32_bf16: A row=lane&15, k=(lane>>4)*8+e; B col=lane&15;
// D col=lane&15, row=(lane>>4)*4+reg (m89-verified).
// ---------------------------------------------------------------------------
template<bool FINAL>
__global__ __launch_bounds__(256) void sage_mfma_k(
    const ushort* __restrict__ aggh, const ushort* __restrict__ aggl,
    const ushort* __restrict__ xh,
    const ushort* __restrict__ wth, const ushort* __restrict__ wtl,
    const float* __restrict__ bias,
    ushort* __restrict__ s_out,
    const float* __restrict__ lin_w, const float* __restrict__ lin_b,
    float* __restrict__ out, int M)
{
    __shared__ __align__(16) ushort Ahs[8][4][64][8];   // 32 KB: agg+x hi
    __shared__ __align__(16) ushort Als[4][4][64][8];   // 16 KB: agg lo
    __shared__ float lps[2][32][2];                     // FINAL combine

    const int t    = threadIdx.x;
    const int rb   = blockIdx.x * 64;
    const int wid  = t >> 6;
    const int wm   = wid >> 1;
    const int wn   = wid & 1;
    const int lane = t & 63;
    const int lr   = lane & 15;
    const int kg   = lane >> 4;

    {
        int row = t >> 2, q = t & 3;
        int grow = rb + row;
        bool ok = grow < M;
        #pragma unroll
        for (int i = 0; i < 8; ++i) {
            const ushort* sp = (i < 4)
                ? aggh + (size_t)grow * 128 + i * 32 + q * 8
                : xh   + (size_t)grow * 128 + (i - 4) * 32 + q * 8;
            uint4 v = make_uint4(0, 0, 0, 0);
            if (ok) v = *(const uint4*)sp;
            *(uint4*)&Ahs[i][q][row][0] = v;
        }
        #pragma unroll
        for (int i = 0; i < 4; ++i) {
            const ushort* sp = aggl + (size_t)grow * 128 + i * 32 + q * 8;
            uint4 v = make_uint4(0, 0, 0, 0);
            if (ok) v = *(const uint4*)sp;
            *(uint4*)&Als[i][q][row][0] = v;
        }
    }
    __syncthreads();

    f32x4 acc[2][4] = {};
    #pragma unroll
    for (int ks = 0; ks < 8; ++ks) {
        const bool isAgg = (ks < 4);
        bf16x8 ah[2], al[2], bh[4], bl[4];
        #pragma unroll
        for (int nt = 0; nt < 4; ++nt) {
            int c = wn * 64 + nt * 16 + lr;
            size_t off = ((size_t)(ks * 4 + kg) * 128 + c) * 8;
            bh[nt] = *(const bf16x8*)(wth + off);
            bl[nt] = *(const bf16x8*)(wtl + off);
        }
        #pragma unroll
        for (int mt = 0; mt < 2; ++mt) {
            int r = wm * 32 + mt * 16 + lr;
            ah[mt] = *(const bf16x8*)&Ahs[ks][kg][r][0];
            al[mt] = isAgg ? *(const bf16x8*)&Als[ks][kg][r][0] : ah[mt];
        }
        #pragma unroll
        for (int mt = 0; mt < 2; ++mt) {
            #pragma unroll
            for (int nt = 0; nt < 4; ++nt) {
                acc[mt][nt] = __builtin_amdgcn_mfma_f32_16x16x32_bf16(
                    ah[mt], bh[nt], acc[mt][nt], 0, 0, 0);
                acc[mt][nt] = __builtin_amdgcn_mfma_f32_16x16x32_bf16(
                    ah[mt], bl[nt], acc[mt][nt], 0, 0, 0);
                if (isAgg)
                    acc[mt][nt] = __builtin_amdgcn_mfma_f32_16x16x32_bf16(
                        al[mt], bh[nt], acc[mt][nt], 0, 0, 0);
            }
        }
    }

    if constexpr (FINAL) {
        float pv[2][4][2];
        #pragma unroll
        for (int mt = 0; mt < 2; ++mt) {
            #pragma unroll
            for (int r = 0; r < 4; ++r) {
                float p0 = 0.f, p1 = 0.f;
                #pragma unroll
                for (int nt = 0; nt < 4; ++nt) {
                    int col = wn * 64 + nt * 16 + lr;
                    float v = fmaxf(acc[mt][nt][r] + bias[col], 0.f);
                    float2 lw = *(const float2*)(lin_w + col * 2);
                    p0 += v * lw.x;
                    p1 += v * lw.y;
                }
                #pragma unroll
                for (int off = 1; off < 16; off <<= 1) {
                    p0 += __shfl_xor(p0, off);
                    p1 += __shfl_xor(p1, off);
                }
                pv[mt][r][0] = p0;
                pv[mt][r][1] = p1;
            }
        }
        if (wn == 1 && lr == 0) {
            #pragma unroll
            for (int mt = 0; mt < 2; ++mt)
                #pragma unroll
                for (int r = 0; r < 4; ++r) {
                    int row = mt * 16 + kg * 4 + r;
                    lps[wm][row][0] = pv[mt][r][0];
                    lps[wm][row][1] = pv[mt][r][1];
                }
        }
        __syncthreads();
        if (wn == 0 && lr == 0) {
            #pragma unroll
            for (int mt = 0; mt < 2; ++mt)
                #pragma unroll
                for (int r = 0; r < 4; ++r) {
                    int row = mt * 16 + kg * 4 + r;
                    int grow = rb + wm * 32 + row;
                    if (grow < M) {
                        out[(size_t)grow * 2 + 0] = pv[mt][r][0] + lps[wm][row][0] + lin_b[0];
                        out[(size_t)grow * 2 + 1] = pv[mt][r][1] + lps[wm][row][1] + lin_b[1];
                    }
                }
        }
    } else {
        #pragma unroll
        for (int mt = 0; mt < 2; ++mt) {
            #pragma unroll
            for (int r = 0; r < 4; ++r) {
                int grow = rb + wm * 32 + mt * 16 + kg * 4 + r;
                #pragma unroll
                for (int nt = 0; nt < 4; ++nt) {
                    int col = wn * 64 + nt * 16 + lr;
                    float v = fmaxf(acc[mt][nt][r] + bias[col], 0.f);
                    if (grow < M)
                        s_out[(size_t)grow * 128 + col] = f2bf(v);
                }
            }
        }
    }
}

// ---------------------------------------------------------------------------
extern "C" void kernel_launch(void* const* d_in, const int* in_sizes, int n_in,
                              void* d_out, int out_size, void* d_ws, size_t ws_size,
                              hipStream_t stream)
{
    const float* x_subject = (const float*)d_in[0];
    const float* w1l  = (const float*)d_in[6];
    const float* w1r  = (const float*)d_in[7];
    const float* w2l  = (const float*)d_in[12];
    const float* w2r  = (const float*)d_in[13];
    const float* b1   = (const float*)d_in[16];
    const float* b2   = (const float*)d_in[19];
    const float* linw = (const float*)d_in[20];
    const float* linb = (const float*)d_in[21];
    const int* ss_src = (const int*)d_in[26];
    const int* ss_dst = (const int*)d_in[27];

    // Workspace layout (~66 MB; re-poisoned 0xAA each call):
    // xh/s1h have NS+1 rows (row NS = zero padding row).
    char* wp = (char*)d_ws;
    ushort* xh        = (ushort*)wp; wp += (size_t)(NS + 1) * D * 2;
    ushort* s1h       = (ushort*)wp; wp += (size_t)(NS + 1) * D * 2;
    ushort* aggh      = (ushort*)wp; wp += (size_t)NS * D * 2;
    ushort* aggl      = (ushort*)wp; wp += (size_t)NS * D * 2;
    ushort* wt1h      = (ushort*)wp; wp += 256 * 128 * 2;
    ushort* wt1l      = (ushort*)wp; wp += 256 * 128 * 2;
    ushort* wt2h      = (ushort*)wp; wp += 256 * 128 * 2;
    ushort* wt2l      = (ushort*)wp; wp += 256 * 128 * 2;
    uint*  staging    = (uint*)wp;  wp += (size_t)NBLK * EPB * 4;  // 3.2 MB
    uint*  esrc       = (uint*)wp;  wp += (size_t)NB * BCAP * 4;   // 6.4 MB
    int*   blockhist  = (int*)wp;   wp += (size_t)NBLK * NB * 4;   // 154 KB
    int*   blockstart = (int*)wp;   wp += (size_t)NBLK * NB * 4;   // 154 KB
    int*   deg        = (int*)wp;   wp += NS * 4;
    int*   row_start  = (int*)wp;   wp += NS * 4;

    const int gath_blocks = (NS + 3) / 4;        // 12500
    const int gemm_blocks = (NS + 63) / 64;      // 782

    // ---- precompute bf16 planes + zero pad-rows (1 fused launch) ----
    splitprep_k<<<SPLIT_BLOCKS + PREP_BLOCKS + 1, 256, 0, stream>>>(
        x_subject, xh, s1h, w1l, w1r, w2l, w2r, wt1h, wt1l, wt2h, wt2l);

    // ---- CSR build: 2 kernels, LDS-local, no global atomics/scan ----
    pack_k<<<NBLK, 256, 0, stream>>>(ss_src, ss_dst, staging,
                                     blockhist, blockstart);
    bucket_csr_k<<<NB, 256, 0, stream>>>(staging, blockhist, blockstart,
                                         deg, row_start, esrc);

    // ---- Layer 1 (roi branch is dead code w.r.t. the output) ----
    gather_mean_bf16_k<<<gath_blocks, 256, 0, stream>>>(xh, esrc, row_start,
                                                        deg, aggh, aggl, NS);
    sage_mfma_k<false><<<gemm_blocks, 256, 0, stream>>>(
        aggh, aggl, xh, wt1h, wt1l, b1, s1h, nullptr, nullptr, nullptr, NS);

    // ---- Layer 2 (same CSR) ----
    gather_mean_bf16_k<<<gath_blocks, 256, 0, stream>>>(s1h, esrc, row_start,
                                                        deg, aggh, aggl, NS);
    sage_mfma_k<true><<<gemm_blocks, 256, 0, stream>>>(
        aggh, aggl, s1h, wt2h, wt2l, b2, nullptr, linw, linb, (float*)d_out, NS);
}